// Round 1
// baseline (579.363 us; speedup 1.0000x reference)
//
#include <hip/hip_runtime.h>
#include <cstdint>
#include <cstddef>

// DeepseekV3 MoE on gfx950.
// Design: bf16 MFMA (16x16x32) GEMMs in the m97 structure (global_load_lds
// width-16 staging, 128x128 tile, 4 waves, 4x4 frags). Weights are
// pre-transposed+converted fp32[K][N] -> bf16[N][K] so both GEMM operands are
// K-contiguous. Sparse dispatch: tokens grouped per expert, padded to
// 128-row tiles (max 80 tiles). Expert weights applied at final gather
// (no atomics -> deterministic output).

#define T_TOK 2048
#define DIM   1024
#define NEXP  16
#define FDIM  1024
#define MAXTILES 80
#define MAXSLOTS (MAXTILES*128)

typedef __bf16 bf16x8_t __attribute__((ext_vector_type(8)));
typedef float  f32x4_t  __attribute__((ext_vector_type(4)));
typedef unsigned short ushort8_t __attribute__((ext_vector_type(8)));
typedef unsigned short ushort4_t __attribute__((ext_vector_type(4)));

// ---- workspace layout (bytes) ----
#define OFF_XB     (0UL)            // 2048*1024 bf16        = 4 MB
#define OFF_GATET  (4UL<<20)        // 16*1024*1024 bf16     = 32 MB  [E][F][D]
#define OFF_UPT    (36UL<<20)       // 32 MB
#define OFF_DOWNT  (68UL<<20)       // 32 MB [E][D][F]
#define OFF_SHGT   (100UL<<20)      // [2048][1024] bf16 = 4 MB
#define OFF_SHUT   (104UL<<20)
#define OFF_SHDT   (108UL<<20)      // [1024][2048] bf16 = 4 MB
#define OFF_H      (112UL<<20)      // 10240*1024 bf16 = 20 MB (also act, shH, sh_act)
#define OFF_U      (132UL<<20)      // 20 MB (also shU)
#define OFF_YSLOT  (152UL<<20)      // 20 MB
#define OFF_CTRL   (172UL<<20)
// ctrl sub-offsets
#define CT_COUNTS   0
#define CT_CURSOR   64
#define CT_OFFSETS  128
#define CT_NTILES   192
#define CT_TILEEXP  256
#define CT_SLOTTOK  4096
#define CT_TKSLOT   49152
#define CT_TOPKIDX  81920
#define CT_TOPKW    114688

__device__ __forceinline__ unsigned short f2bf(float f) {
  __bf16 h = (__bf16)f;
  return __builtin_bit_cast(unsigned short, h);
}
__device__ __forceinline__ float bf2f(unsigned short u) {
  unsigned int v = ((unsigned int)u) << 16;
  return __builtin_bit_cast(float, v);
}
__device__ __forceinline__ void gld16(const void* g, void* l) {
  __builtin_amdgcn_global_load_lds(
      (const __attribute__((address_space(1))) void*)(g),
      (__attribute__((address_space(3))) void*)(l), 16, 0, 0);
}

// ---- fp32 -> bf16 elementwise ----
__global__ void k_cvt(const float* __restrict__ src, unsigned short* __restrict__ dst, int n4) {
  int i = blockIdx.x * blockDim.x + threadIdx.x;
  if (i >= n4) return;
  float4 v = ((const float4*)src)[i];
  ushort4_t o;
  o[0] = f2bf(v.x); o[1] = f2bf(v.y); o[2] = f2bf(v.z); o[3] = f2bf(v.w);
  ((ushort4_t*)dst)[i] = o;
}

// ---- transpose + convert: src fp32 [R][C] -> dst bf16 [C][R]; grid (C/64, R/64, batch) ----
__global__ void k_transpose(const float* __restrict__ src, unsigned short* __restrict__ dst,
                            int R, int C) {
  __shared__ unsigned short tile[64 * 68];
  long b = blockIdx.z;
  src += b * (long)R * C;
  dst += b * (long)R * C;
  int cT = blockIdx.x * 64, rT = blockIdx.y * 64;
  int t = threadIdx.x;
  int rb = t >> 4, cb = t & 15;
  float f[4][4];
#pragma unroll
  for (int i = 0; i < 4; i++) {
    float4 v = *(const float4*)(src + (long)(rT + 4 * rb + i) * C + cT + 4 * cb);
    f[i][0] = v.x; f[i][1] = v.y; f[i][2] = v.z; f[i][3] = v.w;
  }
#pragma unroll
  for (int j = 0; j < 4; j++) {
    ushort4_t o;
    o[0] = f2bf(f[0][j]); o[1] = f2bf(f[1][j]); o[2] = f2bf(f[2][j]); o[3] = f2bf(f[3][j]);
    int c = 4 * cb + j;
    *(ushort4_t*)&tile[c * 68 + 4 * rb] = o;
  }
  __syncthreads();
#pragma unroll
  for (int p = 0; p < 2; p++) {
    int q = t + 256 * p;
    int c = q >> 3, r0 = (q & 7) * 8;
    ushort4_t lo = *(const ushort4_t*)&tile[c * 68 + r0];
    ushort4_t hi = *(const ushort4_t*)&tile[c * 68 + r0 + 4];
    ushort8_t w8 = {lo[0], lo[1], lo[2], lo[3], hi[0], hi[1], hi[2], hi[3]};
    *(ushort8_t*)(dst + (long)(cT + c) * R + rT + r0) = w8;
  }
}

// ---- router: 1 wave per token ----
__global__ void k_router(const float* __restrict__ x, const float* __restrict__ rw,
                         const float* __restrict__ bias, int* __restrict__ topk_idx,
                         float* __restrict__ topk_w, int* __restrict__ counts) {
  int t = blockIdx.x, L = threadIdx.x;
  int e = L & 15, q = L >> 4;
  const float4* xr = (const float4*)(x + (long)t * DIM + q * 256);
  const float4* wr = (const float4*)(rw + (long)e * DIM + q * 256);
  float acc = 0.f;
  for (int i = 0; i < 64; i++) {
    float4 a = xr[i], b = wr[i];
    acc += a.x * b.x + a.y * b.y + a.z * b.z + a.w * b.w;
  }
  __shared__ float part[64];
  __shared__ float s_sc[16], s_s[16];
  part[L] = acc;
  __syncthreads();
  if (L < 16) {
    float logit = part[L] + part[L + 16] + part[L + 32] + part[L + 48];
    float sc = 1.f / (1.f + expf(-logit));
    s_sc[L] = sc;
    s_s[L] = sc + bias[L];
  }
  __syncthreads();
  if (L == 0) {
    float gs[4];
#pragma unroll
    for (int g = 0; g < 4; g++) {
      float m1 = -1e30f, m2 = -1e30f;
      for (int j = 0; j < 4; j++) {
        float v = s_s[g * 4 + j];
        if (v > m1) { m2 = m1; m1 = v; } else if (v > m2) m2 = v;
      }
      gs[g] = m1 + m2;
    }
    int g1 = 0;
    for (int g = 1; g < 4; g++) if (gs[g] > gs[g1]) g1 = g;
    int g2 = -1;
    for (int g = 0; g < 4; g++) { if (g == g1) continue; if (g2 < 0 || gs[g] > gs[g2]) g2 = g; }
    int taken = 0, idx[4];
    float w[4], wsum = 1e-20f;
#pragma unroll
    for (int k = 0; k < 4; k++) {
      float best = -1e30f; int bi = 0;
      for (int e2 = 0; e2 < 16; e2++) {
        if (taken & (1 << e2)) continue;
        int g = e2 >> 2;
        float v = (g == g1 || g == g2) ? s_s[e2] : -1.f;
        if (v > best) { best = v; bi = e2; }
      }
      taken |= 1 << bi; idx[k] = bi;
    }
#pragma unroll
    for (int k = 0; k < 4; k++) { w[k] = s_sc[idx[k]]; wsum += w[k]; }
    float sc2 = 2.5f / wsum;
#pragma unroll
    for (int k = 0; k < 4; k++) {
      topk_idx[t * 4 + k] = idx[k];
      topk_w[t * 4 + k] = w[k] * sc2;
      atomicAdd(&counts[idx[k]], 1);
    }
  }
}

// ---- scan: padded offsets + tile->expert map; fill slot_token with -1 ----
__global__ void k_scan(const int* __restrict__ counts, int* __restrict__ offsets,
                       int* __restrict__ tile_expert, int* __restrict__ n_tiles,
                       int* __restrict__ slot_token) {
  if (threadIdx.x == 0) {
    int cum = 0, tt = 0;
    for (int e = 0; e < NEXP; e++) {
      offsets[e] = cum;
      int nt = (counts[e] + 127) >> 7;
      for (int i = 0; i < nt; i++) tile_expert[tt++] = e;
      cum += nt << 7;
    }
    n_tiles[0] = tt;
  }
  for (int i = threadIdx.x; i < MAXSLOTS; i += blockDim.x) slot_token[i] = -1;
}

// ---- scatter tokens into expert-grouped slots ----
__global__ void k_scatter(const int* __restrict__ topk_idx, const int* __restrict__ offsets,
                          int* __restrict__ cursor, int* __restrict__ slot_token,
                          int* __restrict__ tk_slot) {
  int id = blockIdx.x * blockDim.x + threadIdx.x;
  if (id >= T_TOK * 4) return;
  int e = topk_idx[id];
  int pos = offsets[e] + atomicAdd(&cursor[e], 1);
  slot_token[pos] = id >> 2;
  tk_slot[id] = pos;
}

// ---- GEMM: 128x128 tile, BK=32, 256 thr, m97-style staging.
// MODE 0: routed gate/up (A gathered via slot_token; by<8 gate, else up)
// MODE 1: routed down   (A = act slots; out yslot bf16)
// MODE 2: shared gate/up (A = xb; by<16 gate else up; out width 2048)
// MODE 3: shared down   (A = sh_act K=2048; out fp32 d_out)
template <int MODE>
__global__ __launch_bounds__(256) void k_gemm(
    const unsigned short* __restrict__ Abase, const unsigned short* __restrict__ B0,
    const unsigned short* __restrict__ B1, unsigned short* __restrict__ O0,
    unsigned short* __restrict__ O1, float* __restrict__ OF,
    const int* __restrict__ slot_token, const int* __restrict__ tile_expert,
    const int* __restrict__ n_tiles) {
  constexpr int KT = (MODE == 3) ? 64 : 32;
  constexpr int AW = (MODE == 3) ? 2048 : 1024;
  constexpr int BW = (MODE == 3) ? 2048 : 1024;
  int bx = blockIdx.x, by = blockIdx.y;
  if (MODE == 0 || MODE == 1) { if (bx >= n_tiles[0]) return; }
  const unsigned short* Bp;
  int n0;
  if (MODE == 0) { int e = tile_expert[bx]; Bp = (by < 8 ? B0 : B1) + (size_t)e * 1024 * 1024; n0 = (by & 7) * 128; }
  else if (MODE == 1) { int e = tile_expert[bx]; Bp = B0 + (size_t)e * 1024 * 1024; n0 = by * 128; }
  else if (MODE == 2) { Bp = (by < 16 ? B0 : B1); n0 = (by & 15) * 128; }
  else { Bp = B0; n0 = by * 128; }

  __shared__ unsigned short sA[128 * 32];
  __shared__ unsigned short sB[128 * 32];

  int tid = threadIdx.x;
  int w = tid >> 6, L = tid & 63;
  int c0 = w * 128 + L, c1 = c0 + 64;
  int ar0 = c0 >> 2, ar1 = c1 >> 2;
  long arow0, arow1;
  if (MODE == 0) {
    int t0 = slot_token[bx * 128 + ar0]; if (t0 < 0) t0 = 0;
    int t1 = slot_token[bx * 128 + ar1]; if (t1 < 0) t1 = 0;
    arow0 = t0; arow1 = t1;
  } else {
    arow0 = bx * 128 + ar0; arow1 = bx * 128 + ar1;
  }
  const char* aA = (const char*)(Abase + arow0 * AW) + (c0 & 3) * 16;
  const char* aB = (const char*)(Abase + arow1 * AW) + (c1 & 3) * 16;
  const char* bA = (const char*)(Bp + (size_t)(n0 + ar0) * BW) + (c0 & 3) * 16;
  const char* bB = (const char*)(Bp + (size_t)(n0 + ar1) * BW) + (c1 & 3) * 16;
  char* sAu0 = (char*)sA + (w * 128) * 16;
  char* sAu1 = (char*)sA + (w * 128 + 64) * 16;
  char* sBu0 = (char*)sB + (w * 128) * 16;
  char* sBu1 = (char*)sB + (w * 128 + 64) * 16;

  f32x4_t acc[4][4];
#pragma unroll
  for (int i = 0; i < 4; i++)
#pragma unroll
    for (int j = 0; j < 4; j++) acc[i][j] = f32x4_t{0.f, 0.f, 0.f, 0.f};

  int mb = (w >> 1) * 64, nb = (w & 1) * 64;
  int lr = L & 15, k8 = (L >> 4) * 8;

  for (int kt = 0; kt < KT; ++kt) {
    gld16(aA, sAu0); gld16(aB, sAu1);
    gld16(bA, sBu0); gld16(bB, sBu1);
    aA += 64; aB += 64; bA += 64; bB += 64;
    __syncthreads();
    bf16x8_t af[4], bfv[4];
#pragma unroll
    for (int i = 0; i < 4; i++) af[i] = *(const bf16x8_t*)(sA + (mb + 16 * i + lr) * 32 + k8);
#pragma unroll
    for (int i = 0; i < 4; i++) bfv[i] = *(const bf16x8_t*)(sB + (nb + 16 * i + lr) * 32 + k8);
#pragma unroll
    for (int i = 0; i < 4; i++)
#pragma unroll
      for (int j = 0; j < 4; j++)
        acc[i][j] = __builtin_amdgcn_mfma_f32_16x16x32_bf16(af[i], bfv[j], acc[i][j], 0, 0, 0);
    __syncthreads();
  }

  int quad = L >> 4;
#pragma unroll
  for (int i = 0; i < 4; i++) {
    int rowb = bx * 128 + mb + 16 * i + quad * 4;
#pragma unroll
    for (int j = 0; j < 4; j++) {
      int col = n0 + nb + 16 * j + lr;
#pragma unroll
      for (int r = 0; r < 4; r++) {
        float v = acc[i][j][r];
        if (MODE == 0) (by < 8 ? O0 : O1)[(size_t)(rowb + r) * 1024 + col] = f2bf(v);
        else if (MODE == 1) O0[(size_t)(rowb + r) * 1024 + col] = f2bf(v);
        else if (MODE == 2) (by < 16 ? O0 : O1)[(size_t)(rowb + r) * 2048 + col] = f2bf(v);
        else OF[(size_t)(rowb + r) * 1024 + col] = v;
      }
    }
  }
}

// ---- silu(h)*u elementwise (in-place into h allowed) ----
__global__ void k_silu_mul(const unsigned short* h, const unsigned short* u,
                           unsigned short* o, int n4) {
  int i = blockIdx.x * blockDim.x + threadIdx.x;
  if (i >= n4) return;
  ushort4_t hv = ((const ushort4_t*)h)[i];
  ushort4_t uv = ((const ushort4_t*)u)[i];
  ushort4_t ov;
#pragma unroll
  for (int j = 0; j < 4; j++) {
    float hf = bf2f(hv[j]);
    float uf = bf2f(uv[j]);
    ov[j] = f2bf(hf / (1.f + expf(-hf)) * uf);
  }
  ((ushort4_t*)o)[i] = ov;
}

// ---- final gather: out[t][d] += sum_k w[t][k] * yslot[slot(t,k)][d] ----
__global__ void k_gather(float* __restrict__ out, const unsigned short* __restrict__ yslot,
                         const int* __restrict__ tk_slot, const float* __restrict__ topk_w) {
  int t = blockIdx.x, tid = threadIdx.x;
  int4 sl = ((const int4*)tk_slot)[t];
  float4 wv = ((const float4*)topk_w)[t];
  int d = 4 * tid;
  float4 o = *(float4*)(out + (size_t)t * 1024 + d);
  const int s[4] = {sl.x, sl.y, sl.z, sl.w};
  const float wk[4] = {wv.x, wv.y, wv.z, wv.w};
#pragma unroll
  for (int k = 0; k < 4; k++) {
    ushort4_t y = *(const ushort4_t*)(yslot + (size_t)s[k] * 1024 + d);
    o.x += wk[k] * bf2f(y[0]);
    o.y += wk[k] * bf2f(y[1]);
    o.z += wk[k] * bf2f(y[2]);
    o.w += wk[k] * bf2f(y[3]);
  }
  *(float4*)(out + (size_t)t * 1024 + d) = o;
}

extern "C" void kernel_launch(void* const* d_in, const int* in_sizes, int n_in,
                              void* d_out, int out_size, void* d_ws, size_t ws_size,
                              hipStream_t stream) {
  const float* x = (const float*)d_in[0];
  const float* rw = (const float*)d_in[1];
  const float* bias = (const float*)d_in[2];
  const float* gw = (const float*)d_in[3];
  const float* uw = (const float*)d_in[4];
  const float* dw = (const float*)d_in[5];
  const float* sg = (const float*)d_in[6];
  const float* su = (const float*)d_in[7];
  const float* sd = (const float*)d_in[8];
  float* out = (float*)d_out;
  char* ws = (char*)d_ws;

  unsigned short* xb    = (unsigned short*)(ws + OFF_XB);
  unsigned short* gateT = (unsigned short*)(ws + OFF_GATET);
  unsigned short* upT   = (unsigned short*)(ws + OFF_UPT);
  unsigned short* downT = (unsigned short*)(ws + OFF_DOWNT);
  unsigned short* shGT  = (unsigned short*)(ws + OFF_SHGT);
  unsigned short* shUT  = (unsigned short*)(ws + OFF_SHUT);
  unsigned short* shDT  = (unsigned short*)(ws + OFF_SHDT);
  unsigned short* Hbuf  = (unsigned short*)(ws + OFF_H);
  unsigned short* Ubuf  = (unsigned short*)(ws + OFF_U);
  unsigned short* yslot = (unsigned short*)(ws + OFF_YSLOT);
  char* ctrl = ws + OFF_CTRL;
  int* counts      = (int*)(ctrl + CT_COUNTS);
  int* cursor      = (int*)(ctrl + CT_CURSOR);
  int* offsets_    = (int*)(ctrl + CT_OFFSETS);
  int* n_tiles     = (int*)(ctrl + CT_NTILES);
  int* tile_expert = (int*)(ctrl + CT_TILEEXP);
  int* slot_token  = (int*)(ctrl + CT_SLOTTOK);
  int* tk_slot     = (int*)(ctrl + CT_TKSLOT);
  int* topk_idx    = (int*)(ctrl + CT_TOPKIDX);
  float* topk_w    = (float*)(ctrl + CT_TOPKW);

  hipMemsetAsync(ctrl, 0, 256, stream);
  k_cvt<<<2048, 256, 0, stream>>>(x, xb, T_TOK * DIM / 4);
  k_transpose<<<dim3(16, 16, 16), 256, 0, stream>>>(gw, gateT, 1024, 1024);
  k_transpose<<<dim3(16, 16, 16), 256, 0, stream>>>(uw, upT, 1024, 1024);
  k_transpose<<<dim3(16, 16, 16), 256, 0, stream>>>(dw, downT, 1024, 1024);
  k_transpose<<<dim3(32, 16, 1), 256, 0, stream>>>(sg, shGT, 1024, 2048);
  k_transpose<<<dim3(32, 16, 1), 256, 0, stream>>>(su, shUT, 1024, 2048);
  k_transpose<<<dim3(16, 32, 1), 256, 0, stream>>>(sd, shDT, 2048, 1024);
  k_router<<<2048, 64, 0, stream>>>(x, rw, bias, topk_idx, topk_w, counts);
  k_scan<<<1, 256, 0, stream>>>(counts, offsets_, tile_expert, n_tiles, slot_token);
  k_scatter<<<32, 256, 0, stream>>>(topk_idx, offsets_, cursor, slot_token, tk_slot);
  // routed gate/up -> H,U ; act = silu(H)*U in place into Hbuf
  k_gemm<0><<<dim3(MAXTILES, 16), 256, 0, stream>>>(xb, gateT, upT, Hbuf, Ubuf, nullptr,
                                                    slot_token, tile_expert, n_tiles);
  k_silu_mul<<<MAXSLOTS, 256, 0, stream>>>(Hbuf, Ubuf, Hbuf, MAXSLOTS * 1024 / 4);
  // routed down -> yslot
  k_gemm<1><<<dim3(MAXTILES, 8), 256, 0, stream>>>(Hbuf, downT, nullptr, yslot, nullptr, nullptr,
                                                   slot_token, tile_expert, n_tiles);
  // shared gate/up -> shH(Hbuf), shU(Ubuf); sh_act in place into Hbuf
  k_gemm<2><<<dim3(16, 32), 256, 0, stream>>>(xb, shGT, shUT, Hbuf, Ubuf, nullptr,
                                              slot_token, tile_expert, n_tiles);
  k_silu_mul<<<4096, 256, 0, stream>>>(Hbuf, Ubuf, Hbuf, T_TOK * 2048 / 4);
  // shared down -> out (fp32, full overwrite)
  k_gemm<3><<<dim3(16, 8), 256, 0, stream>>>(Hbuf, shDT, nullptr, nullptr, nullptr, out,
                                             slot_token, tile_expert, n_tiles);
  // out += weighted routed contributions
  k_gather<<<2048, 256, 0, stream>>>(out, yslot, tk_slot, topk_w);
}

// Round 2
// 568.692 us; speedup vs baseline: 1.0188x; 1.0188x over previous
//
#include <hip/hip_runtime.h>
#include <cstdint>
#include <cstddef>

// DeepseekV3 MoE on gfx950.
// Design: bf16 MFMA (16x16x32) GEMMs in the m97 structure (global_load_lds
// width-16 staging, 128x128 tile, 4 waves, 4x4 frags). Weights are
// pre-transposed+converted fp32[K][N] -> bf16[N][K] so both GEMM operands are
// K-contiguous. Sparse dispatch: tokens grouped per expert, padded to
// 128-row tiles (max 80 tiles). Expert weights applied at final gather
// (no atomics -> deterministic output).
// R1: k_router rewritten — 1 block (256 thr) per token, coalesced D-split
// loads + shfl butterfly reduce. Old version was 1 wave/token with scattered
// loads: 117 us at 1.9% VALUBusy (latency-bound). Routing math stays fp32
// (top-k tie semantics must match jax exactly).

#define T_TOK 2048
#define DIM   1024
#define NEXP  16
#define FDIM  1024
#define MAXTILES 80
#define MAXSLOTS (MAXTILES*128)

typedef __bf16 bf16x8_t __attribute__((ext_vector_type(8)));
typedef float  f32x4_t  __attribute__((ext_vector_type(4)));
typedef unsigned short ushort8_t __attribute__((ext_vector_type(8)));
typedef unsigned short ushort4_t __attribute__((ext_vector_type(4)));

// ---- workspace layout (bytes) ----
#define OFF_XB     (0UL)            // 2048*1024 bf16        = 4 MB
#define OFF_GATET  (4UL<<20)        // 16*1024*1024 bf16     = 32 MB  [E][F][D]
#define OFF_UPT    (36UL<<20)       // 32 MB
#define OFF_DOWNT  (68UL<<20)       // 32 MB [E][D][F]
#define OFF_SHGT   (100UL<<20)      // [2048][1024] bf16 = 4 MB
#define OFF_SHUT   (104UL<<20)
#define OFF_SHDT   (108UL<<20)      // [1024][2048] bf16 = 4 MB
#define OFF_H      (112UL<<20)      // 10240*1024 bf16 = 20 MB (also act, shH, sh_act)
#define OFF_U      (132UL<<20)      // 20 MB (also shU)
#define OFF_YSLOT  (152UL<<20)      // 20 MB
#define OFF_CTRL   (172UL<<20)
// ctrl sub-offsets
#define CT_COUNTS   0
#define CT_CURSOR   64
#define CT_OFFSETS  128
#define CT_NTILES   192
#define CT_TILEEXP  256
#define CT_SLOTTOK  4096
#define CT_TKSLOT   49152
#define CT_TOPKIDX  81920
#define CT_TOPKW    114688

__device__ __forceinline__ unsigned short f2bf(float f) {
  __bf16 h = (__bf16)f;
  return __builtin_bit_cast(unsigned short, h);
}
__device__ __forceinline__ float bf2f(unsigned short u) {
  unsigned int v = ((unsigned int)u) << 16;
  return __builtin_bit_cast(float, v);
}
__device__ __forceinline__ void gld16(const void* g, void* l) {
  __builtin_amdgcn_global_load_lds(
      (const __attribute__((address_space(1))) void*)(g),
      (__attribute__((address_space(3))) void*)(l), 16, 0, 0);
}

// ---- fp32 -> bf16 elementwise ----
__global__ void k_cvt(const float* __restrict__ src, unsigned short* __restrict__ dst, int n4) {
  int i = blockIdx.x * blockDim.x + threadIdx.x;
  if (i >= n4) return;
  float4 v = ((const float4*)src)[i];
  ushort4_t o;
  o[0] = f2bf(v.x); o[1] = f2bf(v.y); o[2] = f2bf(v.z); o[3] = f2bf(v.w);
  ((ushort4_t*)dst)[i] = o;
}

// ---- transpose + convert: src fp32 [R][C] -> dst bf16 [C][R]; grid (C/64, R/64, batch) ----
__global__ void k_transpose(const float* __restrict__ src, unsigned short* __restrict__ dst,
                            int R, int C) {
  __shared__ unsigned short tile[64 * 68];
  long b = blockIdx.z;
  src += b * (long)R * C;
  dst += b * (long)R * C;
  int cT = blockIdx.x * 64, rT = blockIdx.y * 64;
  int t = threadIdx.x;
  int rb = t >> 4, cb = t & 15;
  float f[4][4];
#pragma unroll
  for (int i = 0; i < 4; i++) {
    float4 v = *(const float4*)(src + (long)(rT + 4 * rb + i) * C + cT + 4 * cb);
    f[i][0] = v.x; f[i][1] = v.y; f[i][2] = v.z; f[i][3] = v.w;
  }
#pragma unroll
  for (int j = 0; j < 4; j++) {
    ushort4_t o;
    o[0] = f2bf(f[0][j]); o[1] = f2bf(f[1][j]); o[2] = f2bf(f[2][j]); o[3] = f2bf(f[3][j]);
    int c = 4 * cb + j;
    *(ushort4_t*)&tile[c * 68 + 4 * rb] = o;
  }
  __syncthreads();
#pragma unroll
  for (int p = 0; p < 2; p++) {
    int q = t + 256 * p;
    int c = q >> 3, r0 = (q & 7) * 8;
    ushort4_t lo = *(const ushort4_t*)&tile[c * 68 + r0];
    ushort4_t hi = *(const ushort4_t*)&tile[c * 68 + r0 + 4];
    ushort8_t w8 = {lo[0], lo[1], lo[2], lo[3], hi[0], hi[1], hi[2], hi[3]};
    *(ushort8_t*)(dst + (long)(cT + c) * R + rT + r0) = w8;
  }
}

// ---- router: 1 block (256 thr) per token; coalesced D-split + butterfly ----
__global__ __launch_bounds__(256) void k_router(
    const float* __restrict__ x, const float* __restrict__ rw,
    const float* __restrict__ bias, int* __restrict__ topk_idx,
    float* __restrict__ topk_w, int* __restrict__ counts) {
  int t = blockIdx.x, tid = threadIdx.x;
  int wv = tid >> 6, lane = tid & 63;
  // thread tid covers D elements [4*tid, 4*tid+4)
  float4 xv = ((const float4*)(x + (size_t)t * DIM))[tid];
  float part[NEXP];
#pragma unroll
  for (int e = 0; e < NEXP; e++) {
    float4 wr = ((const float4*)(rw + (size_t)e * DIM))[tid];
    part[e] = xv.x * wr.x + xv.y * wr.y + xv.z * wr.z + xv.w * wr.w;
  }
  __shared__ float wsum_s[4 * NEXP];
  __shared__ float s_sc[NEXP], s_s[NEXP];
#pragma unroll
  for (int e = 0; e < NEXP; e++) {
    float v = part[e];
#pragma unroll
    for (int off = 32; off; off >>= 1) v += __shfl_xor(v, off, 64);
    if (lane == 0) wsum_s[wv * NEXP + e] = v;
  }
  __syncthreads();
  if (tid < NEXP) {
    float logit = wsum_s[tid] + wsum_s[NEXP + tid] + wsum_s[2 * NEXP + tid] +
                  wsum_s[3 * NEXP + tid];
    float sc = 1.f / (1.f + expf(-logit));
    s_sc[tid] = sc;
    s_s[tid] = sc + bias[tid];
  }
  __syncthreads();
  if (tid == 0) {
    float gs[4];
#pragma unroll
    for (int g = 0; g < 4; g++) {
      float m1 = -1e30f, m2 = -1e30f;
      for (int j = 0; j < 4; j++) {
        float v = s_s[g * 4 + j];
        if (v > m1) { m2 = m1; m1 = v; } else if (v > m2) m2 = v;
      }
      gs[g] = m1 + m2;
    }
    int g1 = 0;
    for (int g = 1; g < 4; g++) if (gs[g] > gs[g1]) g1 = g;
    int g2 = -1;
    for (int g = 0; g < 4; g++) { if (g == g1) continue; if (g2 < 0 || gs[g] > gs[g2]) g2 = g; }
    int taken = 0, idx[4];
    float w[4], wsum = 1e-20f;
#pragma unroll
    for (int k = 0; k < 4; k++) {
      float best = -1e30f; int bi = 0;
      for (int e2 = 0; e2 < 16; e2++) {
        if (taken & (1 << e2)) continue;
        int g = e2 >> 2;
        float v = (g == g1 || g == g2) ? s_s[e2] : -1.f;
        if (v > best) { best = v; bi = e2; }
      }
      taken |= 1 << bi; idx[k] = bi;
    }
#pragma unroll
    for (int k = 0; k < 4; k++) { w[k] = s_sc[idx[k]]; wsum += w[k]; }
    float sc2 = 2.5f / wsum;
#pragma unroll
    for (int k = 0; k < 4; k++) {
      topk_idx[t * 4 + k] = idx[k];
      topk_w[t * 4 + k] = w[k] * sc2;
      atomicAdd(&counts[idx[k]], 1);
    }
  }
}

// ---- scan: padded offsets + tile->expert map; fill slot_token with -1 ----
__global__ void k_scan(const int* __restrict__ counts, int* __restrict__ offsets,
                       int* __restrict__ tile_expert, int* __restrict__ n_tiles,
                       int* __restrict__ slot_token) {
  if (threadIdx.x == 0) {
    int cum = 0, tt = 0;
    for (int e = 0; e < NEXP; e++) {
      offsets[e] = cum;
      int nt = (counts[e] + 127) >> 7;
      for (int i = 0; i < nt; i++) tile_expert[tt++] = e;
      cum += nt << 7;
    }
    n_tiles[0] = tt;
  }
  for (int i = threadIdx.x; i < MAXSLOTS; i += blockDim.x) slot_token[i] = -1;
}

// ---- scatter tokens into expert-grouped slots ----
__global__ void k_scatter(const int* __restrict__ topk_idx, const int* __restrict__ offsets,
                          int* __restrict__ cursor, int* __restrict__ slot_token,
                          int* __restrict__ tk_slot) {
  int id = blockIdx.x * blockDim.x + threadIdx.x;
  if (id >= T_TOK * 4) return;
  int e = topk_idx[id];
  int pos = offsets[e] + atomicAdd(&cursor[e], 1);
  slot_token[pos] = id >> 2;
  tk_slot[id] = pos;
}

// ---- GEMM: 128x128 tile, BK=32, 256 thr, m97-style staging.
// MODE 0: routed gate/up (A gathered via slot_token; by<8 gate, else up)
// MODE 1: routed down   (A = act slots; out yslot bf16)
// MODE 2: shared gate/up (A = xb; by<16 gate else up; out width 2048)
// MODE 3: shared down   (A = sh_act K=2048; out fp32 d_out)
template <int MODE>
__global__ __launch_bounds__(256) void k_gemm(
    const unsigned short* __restrict__ Abase, const unsigned short* __restrict__ B0,
    const unsigned short* __restrict__ B1, unsigned short* __restrict__ O0,
    unsigned short* __restrict__ O1, float* __restrict__ OF,
    const int* __restrict__ slot_token, const int* __restrict__ tile_expert,
    const int* __restrict__ n_tiles) {
  constexpr int KT = (MODE == 3) ? 64 : 32;
  constexpr int AW = (MODE == 3) ? 2048 : 1024;
  constexpr int BW = (MODE == 3) ? 2048 : 1024;
  int bx = blockIdx.x, by = blockIdx.y;
  if (MODE == 0 || MODE == 1) { if (bx >= n_tiles[0]) return; }
  const unsigned short* Bp;
  int n0;
  if (MODE == 0) { int e = tile_expert[bx]; Bp = (by < 8 ? B0 : B1) + (size_t)e * 1024 * 1024; n0 = (by & 7) * 128; }
  else if (MODE == 1) { int e = tile_expert[bx]; Bp = B0 + (size_t)e * 1024 * 1024; n0 = by * 128; }
  else if (MODE == 2) { Bp = (by < 16 ? B0 : B1); n0 = (by & 15) * 128; }
  else { Bp = B0; n0 = by * 128; }

  __shared__ unsigned short sA[128 * 32];
  __shared__ unsigned short sB[128 * 32];

  int tid = threadIdx.x;
  int w = tid >> 6, L = tid & 63;
  int c0 = w * 128 + L, c1 = c0 + 64;
  int ar0 = c0 >> 2, ar1 = c1 >> 2;
  long arow0, arow1;
  if (MODE == 0) {
    int t0 = slot_token[bx * 128 + ar0]; if (t0 < 0) t0 = 0;
    int t1 = slot_token[bx * 128 + ar1]; if (t1 < 0) t1 = 0;
    arow0 = t0; arow1 = t1;
  } else {
    arow0 = bx * 128 + ar0; arow1 = bx * 128 + ar1;
  }
  const char* aA = (const char*)(Abase + arow0 * AW) + (c0 & 3) * 16;
  const char* aB = (const char*)(Abase + arow1 * AW) + (c1 & 3) * 16;
  const char* bA = (const char*)(Bp + (size_t)(n0 + ar0) * BW) + (c0 & 3) * 16;
  const char* bB = (const char*)(Bp + (size_t)(n0 + ar1) * BW) + (c1 & 3) * 16;
  char* sAu0 = (char*)sA + (w * 128) * 16;
  char* sAu1 = (char*)sA + (w * 128 + 64) * 16;
  char* sBu0 = (char*)sB + (w * 128) * 16;
  char* sBu1 = (char*)sB + (w * 128 + 64) * 16;

  f32x4_t acc[4][4];
#pragma unroll
  for (int i = 0; i < 4; i++)
#pragma unroll
    for (int j = 0; j < 4; j++) acc[i][j] = f32x4_t{0.f, 0.f, 0.f, 0.f};

  int mb = (w >> 1) * 64, nb = (w & 1) * 64;
  int lr = L & 15, k8 = (L >> 4) * 8;

  for (int kt = 0; kt < KT; ++kt) {
    gld16(aA, sAu0); gld16(aB, sAu1);
    gld16(bA, sBu0); gld16(bB, sBu1);
    aA += 64; aB += 64; bA += 64; bB += 64;
    __syncthreads();
    bf16x8_t af[4], bfv[4];
#pragma unroll
    for (int i = 0; i < 4; i++) af[i] = *(const bf16x8_t*)(sA + (mb + 16 * i + lr) * 32 + k8);
#pragma unroll
    for (int i = 0; i < 4; i++) bfv[i] = *(const bf16x8_t*)(sB + (nb + 16 * i + lr) * 32 + k8);
#pragma unroll
    for (int i = 0; i < 4; i++)
#pragma unroll
      for (int j = 0; j < 4; j++)
        acc[i][j] = __builtin_amdgcn_mfma_f32_16x16x32_bf16(af[i], bfv[j], acc[i][j], 0, 0, 0);
    __syncthreads();
  }

  int quad = L >> 4;
#pragma unroll
  for (int i = 0; i < 4; i++) {
    int rowb = bx * 128 + mb + 16 * i + quad * 4;
#pragma unroll
    for (int j = 0; j < 4; j++) {
      int col = n0 + nb + 16 * j + lr;
#pragma unroll
      for (int r = 0; r < 4; r++) {
        float v = acc[i][j][r];
        if (MODE == 0) (by < 8 ? O0 : O1)[(size_t)(rowb + r) * 1024 + col] = f2bf(v);
        else if (MODE == 1) O0[(size_t)(rowb + r) * 1024 + col] = f2bf(v);
        else if (MODE == 2) (by < 16 ? O0 : O1)[(size_t)(rowb + r) * 2048 + col] = f2bf(v);
        else OF[(size_t)(rowb + r) * 1024 + col] = v;
      }
    }
  }
}

// ---- silu(h)*u elementwise (in-place into h allowed) ----
__global__ void k_silu_mul(const unsigned short* h, const unsigned short* u,
                           unsigned short* o, int n4) {
  int i = blockIdx.x * blockDim.x + threadIdx.x;
  if (i >= n4) return;
  ushort4_t hv = ((const ushort4_t*)h)[i];
  ushort4_t uv = ((const ushort4_t*)u)[i];
  ushort4_t ov;
#pragma unroll
  for (int j = 0; j < 4; j++) {
    float hf = bf2f(hv[j]);
    float uf = bf2f(uv[j]);
    ov[j] = f2bf(hf / (1.f + expf(-hf)) * uf);
  }
  ((ushort4_t*)o)[i] = ov;
}

// ---- final gather: out[t][d] += sum_k w[t][k] * yslot[slot(t,k)][d] ----
__global__ void k_gather(float* __restrict__ out, const unsigned short* __restrict__ yslot,
                         const int* __restrict__ tk_slot, const float* __restrict__ topk_w) {
  int t = blockIdx.x, tid = threadIdx.x;
  int4 sl = ((const int4*)tk_slot)[t];
  float4 wv = ((const float4*)topk_w)[t];
  int d = 4 * tid;
  float4 o = *(float4*)(out + (size_t)t * 1024 + d);
  const int s[4] = {sl.x, sl.y, sl.z, sl.w};
  const float wk[4] = {wv.x, wv.y, wv.z, wv.w};
#pragma unroll
  for (int k = 0; k < 4; k++) {
    ushort4_t y = *(const ushort4_t*)(yslot + (size_t)s[k] * 1024 + d);
    o.x += wk[k] * bf2f(y[0]);
    o.y += wk[k] * bf2f(y[1]);
    o.z += wk[k] * bf2f(y[2]);
    o.w += wk[k] * bf2f(y[3]);
  }
  *(float4*)(out + (size_t)t * 1024 + d) = o;
}

extern "C" void kernel_launch(void* const* d_in, const int* in_sizes, int n_in,
                              void* d_out, int out_size, void* d_ws, size_t ws_size,
                              hipStream_t stream) {
  const float* x = (const float*)d_in[0];
  const float* rw = (const float*)d_in[1];
  const float* bias = (const float*)d_in[2];
  const float* gw = (const float*)d_in[3];
  const float* uw = (const float*)d_in[4];
  const float* dw = (const float*)d_in[5];
  const float* sg = (const float*)d_in[6];
  const float* su = (const float*)d_in[7];
  const float* sd = (const float*)d_in[8];
  float* out = (float*)d_out;
  char* ws = (char*)d_ws;

  unsigned short* xb    = (unsigned short*)(ws + OFF_XB);
  unsigned short* gateT = (unsigned short*)(ws + OFF_GATET);
  unsigned short* upT   = (unsigned short*)(ws + OFF_UPT);
  unsigned short* downT = (unsigned short*)(ws + OFF_DOWNT);
  unsigned short* shGT  = (unsigned short*)(ws + OFF_SHGT);
  unsigned short* shUT  = (unsigned short*)(ws + OFF_SHUT);
  unsigned short* shDT  = (unsigned short*)(ws + OFF_SHDT);
  unsigned short* Hbuf  = (unsigned short*)(ws + OFF_H);
  unsigned short* Ubuf  = (unsigned short*)(ws + OFF_U);
  unsigned short* yslot = (unsigned short*)(ws + OFF_YSLOT);
  char* ctrl = ws + OFF_CTRL;
  int* counts      = (int*)(ctrl + CT_COUNTS);
  int* cursor      = (int*)(ctrl + CT_CURSOR);
  int* offsets_    = (int*)(ctrl + CT_OFFSETS);
  int* n_tiles     = (int*)(ctrl + CT_NTILES);
  int* tile_expert = (int*)(ctrl + CT_TILEEXP);
  int* slot_token  = (int*)(ctrl + CT_SLOTTOK);
  int* tk_slot     = (int*)(ctrl + CT_TKSLOT);
  int* topk_idx    = (int*)(ctrl + CT_TOPKIDX);
  float* topk_w    = (float*)(ctrl + CT_TOPKW);

  hipMemsetAsync(ctrl, 0, 256, stream);
  k_cvt<<<2048, 256, 0, stream>>>(x, xb, T_TOK * DIM / 4);
  k_transpose<<<dim3(16, 16, 16), 256, 0, stream>>>(gw, gateT, 1024, 1024);
  k_transpose<<<dim3(16, 16, 16), 256, 0, stream>>>(uw, upT, 1024, 1024);
  k_transpose<<<dim3(16, 16, 16), 256, 0, stream>>>(dw, downT, 1024, 1024);
  k_transpose<<<dim3(32, 16, 1), 256, 0, stream>>>(sg, shGT, 1024, 2048);
  k_transpose<<<dim3(32, 16, 1), 256, 0, stream>>>(su, shUT, 1024, 2048);
  k_transpose<<<dim3(16, 32, 1), 256, 0, stream>>>(sd, shDT, 2048, 1024);
  k_router<<<2048, 256, 0, stream>>>(x, rw, bias, topk_idx, topk_w, counts);
  k_scan<<<1, 256, 0, stream>>>(counts, offsets_, tile_expert, n_tiles, slot_token);
  k_scatter<<<32, 256, 0, stream>>>(topk_idx, offsets_, cursor, slot_token, tk_slot);
  // routed gate/up -> H,U ; act = silu(H)*U in place into Hbuf
  k_gemm<0><<<dim3(MAXTILES, 16), 256, 0, stream>>>(xb, gateT, upT, Hbuf, Ubuf, nullptr,
                                                    slot_token, tile_expert, n_tiles);
  k_silu_mul<<<MAXSLOTS, 256, 0, stream>>>(Hbuf, Ubuf, Hbuf, MAXSLOTS * 1024 / 4);
  // routed down -> yslot
  k_gemm<1><<<dim3(MAXTILES, 8), 256, 0, stream>>>(Hbuf, downT, nullptr, yslot, nullptr, nullptr,
                                                   slot_token, tile_expert, n_tiles);
  // shared gate/up -> shH(Hbuf), shU(Ubuf); sh_act in place into Hbuf
  k_gemm<2><<<dim3(16, 32), 256, 0, stream>>>(xb, shGT, shUT, Hbuf, Ubuf, nullptr,
                                              slot_token, tile_expert, n_tiles);
  k_silu_mul<<<4096, 256, 0, stream>>>(Hbuf, Ubuf, Hbuf, T_TOK * 2048 / 4);
  // shared down -> out (fp32, full overwrite)
  k_gemm<3><<<dim3(16, 8), 256, 0, stream>>>(Hbuf, shDT, nullptr, nullptr, nullptr, out,
                                             slot_token, tile_expert, n_tiles);
  // out += weighted routed contributions
  k_gather<<<2048, 256, 0, stream>>>(out, yslot, tk_slot, topk_w);
}

// Round 3
// 491.802 us; speedup vs baseline: 1.1780x; 1.1563x over previous
//
#include <hip/hip_runtime.h>
#include <cstdint>
#include <cstddef>

// DeepseekV3 MoE on gfx950.
// Design: bf16 MFMA (16x16x32) GEMMs in the m97 structure (global_load_lds
// width-16 staging, 128x128 tile, 4 waves, 4x4 frags). Weights are
// pre-transposed+converted fp32[K][N] -> bf16[N][K] so both GEMM operands are
// K-contiguous. Sparse dispatch: tokens grouped per expert, padded to
// 128-row tiles (max 80 tiles). Expert weights applied at final gather
// (no atomics -> deterministic output).
// R1: router 1 block/token, coalesced loads + shfl butterfly.
// R2->R3: REMOVED all global atomics from routing. Both R0/R1 routers sat at
// ~110 us with all pipes idle -> drain tail of 8192 device-scope atomicAdds
// to ONE cacheline (counts[16]); k_scatter had the same pattern (cursor[16]).
// Counting/prefix/scatter now done atomic-free in one 256-thread block
// (k_route_post). Router tail reads scores from registers, not LDS.

#define T_TOK 2048
#define DIM   1024
#define NEXP  16
#define FDIM  1024
#define MAXTILES 80
#define MAXSLOTS (MAXTILES*128)

typedef __bf16 bf16x8_t __attribute__((ext_vector_type(8)));
typedef float  f32x4_t  __attribute__((ext_vector_type(4)));
typedef unsigned short ushort8_t __attribute__((ext_vector_type(8)));
typedef unsigned short ushort4_t __attribute__((ext_vector_type(4)));

// ---- workspace layout (bytes) ----
#define OFF_XB     (0UL)            // 2048*1024 bf16        = 4 MB
#define OFF_GATET  (4UL<<20)        // 16*1024*1024 bf16     = 32 MB  [E][F][D]
#define OFF_UPT    (36UL<<20)       // 32 MB
#define OFF_DOWNT  (68UL<<20)       // 32 MB [E][D][F]
#define OFF_SHGT   (100UL<<20)      // [2048][1024] bf16 = 4 MB
#define OFF_SHUT   (104UL<<20)
#define OFF_SHDT   (108UL<<20)      // [1024][2048] bf16 = 4 MB
#define OFF_H      (112UL<<20)      // 10240*1024 bf16 = 20 MB (also act, shH, sh_act)
#define OFF_U      (132UL<<20)      // 20 MB (also shU)
#define OFF_YSLOT  (152UL<<20)      // 20 MB
#define OFF_CTRL   (172UL<<20)
// ctrl sub-offsets
#define CT_OFFSETS  128
#define CT_NTILES   192
#define CT_TILEEXP  256
#define CT_SLOTTOK  4096
#define CT_TKSLOT   49152
#define CT_TOPKIDX  81920
#define CT_TOPKW    114688

__device__ __forceinline__ unsigned short f2bf(float f) {
  __bf16 h = (__bf16)f;
  return __builtin_bit_cast(unsigned short, h);
}
__device__ __forceinline__ float bf2f(unsigned short u) {
  unsigned int v = ((unsigned int)u) << 16;
  return __builtin_bit_cast(float, v);
}
__device__ __forceinline__ void gld16(const void* g, void* l) {
  __builtin_amdgcn_global_load_lds(
      (const __attribute__((address_space(1))) void*)(g),
      (__attribute__((address_space(3))) void*)(l), 16, 0, 0);
}

// ---- fp32 -> bf16 elementwise ----
__global__ void k_cvt(const float* __restrict__ src, unsigned short* __restrict__ dst, int n4) {
  int i = blockIdx.x * blockDim.x + threadIdx.x;
  if (i >= n4) return;
  float4 v = ((const float4*)src)[i];
  ushort4_t o;
  o[0] = f2bf(v.x); o[1] = f2bf(v.y); o[2] = f2bf(v.z); o[3] = f2bf(v.w);
  ((ushort4_t*)dst)[i] = o;
}

// ---- transpose + convert: src fp32 [R][C] -> dst bf16 [C][R]; grid (C/64, R/64, batch) ----
__global__ void k_transpose(const float* __restrict__ src, unsigned short* __restrict__ dst,
                            int R, int C) {
  __shared__ unsigned short tile[64 * 68];
  long b = blockIdx.z;
  src += b * (long)R * C;
  dst += b * (long)R * C;
  int cT = blockIdx.x * 64, rT = blockIdx.y * 64;
  int t = threadIdx.x;
  int rb = t >> 4, cb = t & 15;
  float f[4][4];
#pragma unroll
  for (int i = 0; i < 4; i++) {
    float4 v = *(const float4*)(src + (long)(rT + 4 * rb + i) * C + cT + 4 * cb);
    f[i][0] = v.x; f[i][1] = v.y; f[i][2] = v.z; f[i][3] = v.w;
  }
#pragma unroll
  for (int j = 0; j < 4; j++) {
    ushort4_t o;
    o[0] = f2bf(f[0][j]); o[1] = f2bf(f[1][j]); o[2] = f2bf(f[2][j]); o[3] = f2bf(f[3][j]);
    int c = 4 * cb + j;
    *(ushort4_t*)&tile[c * 68 + 4 * rb] = o;
  }
  __syncthreads();
#pragma unroll
  for (int p = 0; p < 2; p++) {
    int q = t + 256 * p;
    int c = q >> 3, r0 = (q & 7) * 8;
    ushort4_t lo = *(const ushort4_t*)&tile[c * 68 + r0];
    ushort4_t hi = *(const ushort4_t*)&tile[c * 68 + r0 + 4];
    ushort8_t w8 = {lo[0], lo[1], lo[2], lo[3], hi[0], hi[1], hi[2], hi[3]};
    *(ushort8_t*)(dst + (long)(cT + c) * R + rT + r0) = w8;
  }
}

// ---- router: 1 block (256 thr) per token; coalesced D-split + butterfly.
// NO global atomics. tid 0 does top-k from registers.
__global__ __launch_bounds__(256) void k_router(
    const float* __restrict__ x, const float* __restrict__ rw,
    const float* __restrict__ bias, int* __restrict__ topk_idx,
    float* __restrict__ topk_w) {
  int t = blockIdx.x, tid = threadIdx.x;
  int wv = tid >> 6, lane = tid & 63;
  float4 xv = ((const float4*)(x + (size_t)t * DIM))[tid];
  float part[NEXP];
#pragma unroll
  for (int e = 0; e < NEXP; e++) {
    float4 wr = ((const float4*)(rw + (size_t)e * DIM))[tid];
    part[e] = xv.x * wr.x + xv.y * wr.y + xv.z * wr.z + xv.w * wr.w;
  }
  __shared__ float wsum_s[4 * NEXP];
#pragma unroll
  for (int e = 0; e < NEXP; e++) {
    float v = part[e];
#pragma unroll
    for (int off = 32; off; off >>= 1) v += __shfl_xor(v, off, 64);
    if (lane == 0) wsum_s[wv * NEXP + e] = v;
  }
  __syncthreads();
  if (tid == 0) {
    float r_sc[NEXP], r_s[NEXP];
#pragma unroll
    for (int e = 0; e < NEXP; e++) {
      float logit = wsum_s[e] + wsum_s[NEXP + e] + wsum_s[2 * NEXP + e] +
                    wsum_s[3 * NEXP + e];
      float sc = 1.f / (1.f + expf(-logit));
      r_sc[e] = sc;
      r_s[e] = sc + bias[e];
    }
    float gs[4];
#pragma unroll
    for (int g = 0; g < 4; g++) {
      float m1 = -1e30f, m2 = -1e30f;
#pragma unroll
      for (int j = 0; j < 4; j++) {
        float v = r_s[g * 4 + j];
        if (v > m1) { m2 = m1; m1 = v; } else if (v > m2) m2 = v;
      }
      gs[g] = m1 + m2;
    }
    int g1 = 0;
    for (int g = 1; g < 4; g++) if (gs[g] > gs[g1]) g1 = g;
    int g2 = -1;
    for (int g = 0; g < 4; g++) { if (g == g1) continue; if (g2 < 0 || gs[g] > gs[g2]) g2 = g; }
    int taken = 0, idx[4];
    float w[4], wsum = 1e-20f;
#pragma unroll
    for (int k = 0; k < 4; k++) {
      float best = -1e30f; int bi = 0;
#pragma unroll
      for (int e2 = 0; e2 < 16; e2++) {
        if (taken & (1 << e2)) continue;
        int g = e2 >> 2;
        float v = (g == g1 || g == g2) ? r_s[e2] : -1.f;
        if (v > best) { best = v; bi = e2; }
      }
      taken |= 1 << bi; idx[k] = bi;
    }
#pragma unroll
    for (int k = 0; k < 4; k++) { w[k] = r_sc[idx[k]]; wsum += w[k]; }
    float sc2 = 2.5f / wsum;
#pragma unroll
    for (int k = 0; k < 4; k++) {
      topk_idx[t * 4 + k] = idx[k];
      topk_w[t * 4 + k] = w[k] * sc2;
    }
  }
}

// ---- route_post: single block, atomic-free count + scan + scatter ----
// thread tid owns tokens [tid*8, tid*8+8). Deterministic slot assignment:
// expert-major, then token order.
__global__ __launch_bounds__(256) void k_route_post(
    const int* __restrict__ topk_idx, int* __restrict__ offsets,
    int* __restrict__ tile_expert, int* __restrict__ n_tiles,
    int* __restrict__ slot_token, int* __restrict__ tk_slot) {
  __shared__ int cnt[NEXP][257];
  __shared__ int offs[NEXP], tot[NEXP], s_ntiles;
  int tid = threadIdx.x;
  // phase A: local counts
  int4 ent[8];
#pragma unroll
  for (int i = 0; i < 8; i++) ent[i] = ((const int4*)topk_idx)[tid * 8 + i];
  int lc[NEXP];
#pragma unroll
  for (int j = 0; j < NEXP; j++) lc[j] = 0;
#pragma unroll
  for (int i = 0; i < 8; i++) {
    int es[4] = {ent[i].x, ent[i].y, ent[i].z, ent[i].w};
#pragma unroll
    for (int k = 0; k < 4; k++)
#pragma unroll
      for (int j = 0; j < NEXP; j++) lc[j] += (es[k] == j) ? 1 : 0;
  }
#pragma unroll
  for (int j = 0; j < NEXP; j++) cnt[j][tid] = lc[j];
  __syncthreads();
  // phase B: per-expert exclusive scan over 256 chunks (batched-8 reads)
  if (tid < NEXP) {
    int base = 0;
    for (int c = 0; c < 256; c += 8) {
      int v[8];
#pragma unroll
      for (int i = 0; i < 8; i++) v[i] = cnt[tid][c + i];
#pragma unroll
      for (int i = 0; i < 8; i++) { cnt[tid][c + i] = base; base += v[i]; }
    }
    tot[tid] = base;
  }
  __syncthreads();
  // phase C: padded offsets + tile map (thread 0)
  if (tid == 0) {
    int cum = 0, tt = 0;
    for (int e = 0; e < NEXP; e++) {
      offs[e] = cum;
      offsets[e] = cum;
      int nt = (tot[e] + 127) >> 7;
      for (int i = 0; i < nt; i++) tile_expert[tt++] = e;
      cum += nt << 7;
    }
    n_tiles[0] = tt;
    s_ntiles = tt;
  }
  __syncthreads();
  // phase D: fill pad slots with -1 (disjoint from valid slots; no hazard)
  for (int e = 0; e < NEXP; e++) {
    int s0 = offs[e] + tot[e];
    int s1 = offs[e] + (((tot[e] + 127) >> 7) << 7);
    for (int s = s0 + tid; s < s1; s += 256) slot_token[s] = -1;
  }
  // phase E: deterministic scatter
  int lcur[NEXP];
#pragma unroll
  for (int j = 0; j < NEXP; j++) lcur[j] = offs[j] + cnt[j][tid];
#pragma unroll
  for (int i = 0; i < 8; i++) {
    int t = tid * 8 + i;
    int es[4] = {ent[i].x, ent[i].y, ent[i].z, ent[i].w};
#pragma unroll
    for (int k = 0; k < 4; k++) {
      int e = es[k], pos = 0;
#pragma unroll
      for (int j = 0; j < NEXP; j++) pos += (e == j) ? lcur[j] : 0;
#pragma unroll
      for (int j = 0; j < NEXP; j++) lcur[j] += (e == j) ? 1 : 0;
      slot_token[pos] = t;
      tk_slot[t * 4 + k] = pos;
    }
  }
}

// ---- GEMM: 128x128 tile, BK=32, 256 thr, m97-style staging.
// MODE 0: routed gate/up (A gathered via slot_token; by<8 gate, else up)
// MODE 1: routed down   (A = act slots; out yslot bf16)
// MODE 2: shared gate/up (A = xb; by<16 gate else up; out width 2048)
// MODE 3: shared down   (A = sh_act K=2048; out fp32 d_out)
template <int MODE>
__global__ __launch_bounds__(256) void k_gemm(
    const unsigned short* __restrict__ Abase, const unsigned short* __restrict__ B0,
    const unsigned short* __restrict__ B1, unsigned short* __restrict__ O0,
    unsigned short* __restrict__ O1, float* __restrict__ OF,
    const int* __restrict__ slot_token, const int* __restrict__ tile_expert,
    const int* __restrict__ n_tiles) {
  constexpr int KT = (MODE == 3) ? 64 : 32;
  constexpr int AW = (MODE == 3) ? 2048 : 1024;
  constexpr int BW = (MODE == 3) ? 2048 : 1024;
  int bx = blockIdx.x, by = blockIdx.y;
  if (MODE == 0 || MODE == 1) { if (bx >= n_tiles[0]) return; }
  const unsigned short* Bp;
  int n0;
  if (MODE == 0) { int e = tile_expert[bx]; Bp = (by < 8 ? B0 : B1) + (size_t)e * 1024 * 1024; n0 = (by & 7) * 128; }
  else if (MODE == 1) { int e = tile_expert[bx]; Bp = B0 + (size_t)e * 1024 * 1024; n0 = by * 128; }
  else if (MODE == 2) { Bp = (by < 16 ? B0 : B1); n0 = (by & 15) * 128; }
  else { Bp = B0; n0 = by * 128; }

  __shared__ unsigned short sA[128 * 32];
  __shared__ unsigned short sB[128 * 32];

  int tid = threadIdx.x;
  int w = tid >> 6, L = tid & 63;
  int c0 = w * 128 + L, c1 = c0 + 64;
  int ar0 = c0 >> 2, ar1 = c1 >> 2;
  long arow0, arow1;
  if (MODE == 0) {
    int t0 = slot_token[bx * 128 + ar0]; if (t0 < 0) t0 = 0;
    int t1 = slot_token[bx * 128 + ar1]; if (t1 < 0) t1 = 0;
    arow0 = t0; arow1 = t1;
  } else {
    arow0 = bx * 128 + ar0; arow1 = bx * 128 + ar1;
  }
  const char* aA = (const char*)(Abase + arow0 * AW) + (c0 & 3) * 16;
  const char* aB = (const char*)(Abase + arow1 * AW) + (c1 & 3) * 16;
  const char* bA = (const char*)(Bp + (size_t)(n0 + ar0) * BW) + (c0 & 3) * 16;
  const char* bB = (const char*)(Bp + (size_t)(n0 + ar1) * BW) + (c1 & 3) * 16;
  char* sAu0 = (char*)sA + (w * 128) * 16;
  char* sAu1 = (char*)sA + (w * 128 + 64) * 16;
  char* sBu0 = (char*)sB + (w * 128) * 16;
  char* sBu1 = (char*)sB + (w * 128 + 64) * 16;

  f32x4_t acc[4][4];
#pragma unroll
  for (int i = 0; i < 4; i++)
#pragma unroll
    for (int j = 0; j < 4; j++) acc[i][j] = f32x4_t{0.f, 0.f, 0.f, 0.f};

  int mb = (w >> 1) * 64, nb = (w & 1) * 64;
  int lr = L & 15, k8 = (L >> 4) * 8;

  for (int kt = 0; kt < KT; ++kt) {
    gld16(aA, sAu0); gld16(aB, sAu1);
    gld16(bA, sBu0); gld16(bB, sBu1);
    aA += 64; aB += 64; bA += 64; bB += 64;
    __syncthreads();
    bf16x8_t af[4], bfv[4];
#pragma unroll
    for (int i = 0; i < 4; i++) af[i] = *(const bf16x8_t*)(sA + (mb + 16 * i + lr) * 32 + k8);
#pragma unroll
    for (int i = 0; i < 4; i++) bfv[i] = *(const bf16x8_t*)(sB + (nb + 16 * i + lr) * 32 + k8);
#pragma unroll
    for (int i = 0; i < 4; i++)
#pragma unroll
      for (int j = 0; j < 4; j++)
        acc[i][j] = __builtin_amdgcn_mfma_f32_16x16x32_bf16(af[i], bfv[j], acc[i][j], 0, 0, 0);
    __syncthreads();
  }

  int quad = L >> 4;
#pragma unroll
  for (int i = 0; i < 4; i++) {
    int rowb = bx * 128 + mb + 16 * i + quad * 4;
#pragma unroll
    for (int j = 0; j < 4; j++) {
      int col = n0 + nb + 16 * j + lr;
#pragma unroll
      for (int r = 0; r < 4; r++) {
        float v = acc[i][j][r];
        if (MODE == 0) (by < 8 ? O0 : O1)[(size_t)(rowb + r) * 1024 + col] = f2bf(v);
        else if (MODE == 1) O0[(size_t)(rowb + r) * 1024 + col] = f2bf(v);
        else if (MODE == 2) (by < 16 ? O0 : O1)[(size_t)(rowb + r) * 2048 + col] = f2bf(v);
        else OF[(size_t)(rowb + r) * 1024 + col] = v;
      }
    }
  }
}

// ---- silu(h)*u elementwise (in-place into h allowed) ----
__global__ void k_silu_mul(const unsigned short* h, const unsigned short* u,
                           unsigned short* o, int n4) {
  int i = blockIdx.x * blockDim.x + threadIdx.x;
  if (i >= n4) return;
  ushort4_t hv = ((const ushort4_t*)h)[i];
  ushort4_t uv = ((const ushort4_t*)u)[i];
  ushort4_t ov;
#pragma unroll
  for (int j = 0; j < 4; j++) {
    float hf = bf2f(hv[j]);
    float uf = bf2f(uv[j]);
    ov[j] = f2bf(hf / (1.f + expf(-hf)) * uf);
  }
  ((ushort4_t*)o)[i] = ov;
}

// ---- final gather: out[t][d] += sum_k w[t][k] * yslot[slot(t,k)][d] ----
__global__ void k_gather(float* __restrict__ out, const unsigned short* __restrict__ yslot,
                         const int* __restrict__ tk_slot, const float* __restrict__ topk_w) {
  int t = blockIdx.x, tid = threadIdx.x;
  int4 sl = ((const int4*)tk_slot)[t];
  float4 wv = ((const float4*)topk_w)[t];
  int d = 4 * tid;
  float4 o = *(float4*)(out + (size_t)t * 1024 + d);
  const int s[4] = {sl.x, sl.y, sl.z, sl.w};
  const float wk[4] = {wv.x, wv.y, wv.z, wv.w};
#pragma unroll
  for (int k = 0; k < 4; k++) {
    ushort4_t y = *(const ushort4_t*)(yslot + (size_t)s[k] * 1024 + d);
    o.x += wk[k] * bf2f(y[0]);
    o.y += wk[k] * bf2f(y[1]);
    o.z += wk[k] * bf2f(y[2]);
    o.w += wk[k] * bf2f(y[3]);
  }
  *(float4*)(out + (size_t)t * 1024 + d) = o;
}

extern "C" void kernel_launch(void* const* d_in, const int* in_sizes, int n_in,
                              void* d_out, int out_size, void* d_ws, size_t ws_size,
                              hipStream_t stream) {
  const float* x = (const float*)d_in[0];
  const float* rw = (const float*)d_in[1];
  const float* bias = (const float*)d_in[2];
  const float* gw = (const float*)d_in[3];
  const float* uw = (const float*)d_in[4];
  const float* dw = (const float*)d_in[5];
  const float* sg = (const float*)d_in[6];
  const float* su = (const float*)d_in[7];
  const float* sd = (const float*)d_in[8];
  float* out = (float*)d_out;
  char* ws = (char*)d_ws;

  unsigned short* xb    = (unsigned short*)(ws + OFF_XB);
  unsigned short* gateT = (unsigned short*)(ws + OFF_GATET);
  unsigned short* upT   = (unsigned short*)(ws + OFF_UPT);
  unsigned short* downT = (unsigned short*)(ws + OFF_DOWNT);
  unsigned short* shGT  = (unsigned short*)(ws + OFF_SHGT);
  unsigned short* shUT  = (unsigned short*)(ws + OFF_SHUT);
  unsigned short* shDT  = (unsigned short*)(ws + OFF_SHDT);
  unsigned short* Hbuf  = (unsigned short*)(ws + OFF_H);
  unsigned short* Ubuf  = (unsigned short*)(ws + OFF_U);
  unsigned short* yslot = (unsigned short*)(ws + OFF_YSLOT);
  char* ctrl = ws + OFF_CTRL;
  int* offsets_    = (int*)(ctrl + CT_OFFSETS);
  int* n_tiles     = (int*)(ctrl + CT_NTILES);
  int* tile_expert = (int*)(ctrl + CT_TILEEXP);
  int* slot_token  = (int*)(ctrl + CT_SLOTTOK);
  int* tk_slot     = (int*)(ctrl + CT_TKSLOT);
  int* topk_idx    = (int*)(ctrl + CT_TOPKIDX);
  float* topk_w    = (float*)(ctrl + CT_TOPKW);

  k_cvt<<<2048, 256, 0, stream>>>(x, xb, T_TOK * DIM / 4);
  k_transpose<<<dim3(16, 16, 16), 256, 0, stream>>>(gw, gateT, 1024, 1024);
  k_transpose<<<dim3(16, 16, 16), 256, 0, stream>>>(uw, upT, 1024, 1024);
  k_transpose<<<dim3(16, 16, 16), 256, 0, stream>>>(dw, downT, 1024, 1024);
  k_transpose<<<dim3(32, 16, 1), 256, 0, stream>>>(sg, shGT, 1024, 2048);
  k_transpose<<<dim3(32, 16, 1), 256, 0, stream>>>(su, shUT, 1024, 2048);
  k_transpose<<<dim3(16, 32, 1), 256, 0, stream>>>(sd, shDT, 2048, 1024);
  k_router<<<2048, 256, 0, stream>>>(x, rw, bias, topk_idx, topk_w);
  k_route_post<<<1, 256, 0, stream>>>(topk_idx, offsets_, tile_expert, n_tiles,
                                      slot_token, tk_slot);
  // routed gate/up -> H,U ; act = silu(H)*U in place into Hbuf
  k_gemm<0><<<dim3(MAXTILES, 16), 256, 0, stream>>>(xb, gateT, upT, Hbuf, Ubuf, nullptr,
                                                    slot_token, tile_expert, n_tiles);
  k_silu_mul<<<MAXSLOTS, 256, 0, stream>>>(Hbuf, Ubuf, Hbuf, MAXSLOTS * 1024 / 4);
  // routed down -> yslot
  k_gemm<1><<<dim3(MAXTILES, 8), 256, 0, stream>>>(Hbuf, downT, nullptr, yslot, nullptr, nullptr,
                                                   slot_token, tile_expert, n_tiles);
  // shared gate/up -> shH(Hbuf), shU(Ubuf); sh_act in place into Hbuf
  k_gemm<2><<<dim3(16, 32), 256, 0, stream>>>(xb, shGT, shUT, Hbuf, Ubuf, nullptr,
                                              slot_token, tile_expert, n_tiles);
  k_silu_mul<<<4096, 256, 0, stream>>>(Hbuf, Ubuf, Hbuf, T_TOK * 2048 / 4);
  // shared down -> out (fp32, full overwrite)
  k_gemm<3><<<dim3(16, 8), 256, 0, stream>>>(Hbuf, shDT, nullptr, nullptr, nullptr, out,
                                             slot_token, tile_expert, n_tiles);
  // out += weighted routed contributions
  k_gather<<<2048, 256, 0, stream>>>(out, yslot, tk_slot, topk_w);
}

// Round 4
// 475.311 us; speedup vs baseline: 1.2189x; 1.0347x over previous
//
#include <hip/hip_runtime.h>
#include <cstdint>
#include <cstddef>

// DeepseekV3 MoE on gfx950.
// R3->R4:
//  - XOR-swizzle LDS chunk layout (kill 4.65M bank conflicts: 64B rows put
//    ds_read_b128 on 16 of 32 banks; chunk^=(row&3) spreads to all 32).
//  - Fused gate+up+silu GEMM (one block computes both projections, silu in
//    epilogue): removes H/U round-trip (~70 MB) and both k_silu_mul launches,
//    doubles MFMA per barrier.
//  - Grid re-oriented N-major (blockIdx.x = n-tile, width 8/16) so blocks
//    sharing a B tile land on the same XCD (%8 heuristic) -> B refetch ~1x.
//  - Shared-down split-K=2 (grid.z) -> fp32 partials in Ubuf; k_gather sums
//    both slabs + weighted routed (deterministic, no atomics).

#define T_TOK 2048
#define DIM   1024
#define NEXP  16
#define FDIM  1024
#define MAXTILES 80
#define MAXSLOTS (MAXTILES*128)

typedef __bf16 bf16x8_t __attribute__((ext_vector_type(8)));
typedef float  f32x4_t  __attribute__((ext_vector_type(4)));
typedef unsigned short ushort8_t __attribute__((ext_vector_type(8)));
typedef unsigned short ushort4_t __attribute__((ext_vector_type(4)));

// ---- workspace layout (bytes) ----
#define OFF_XB     (0UL)            // 2048*1024 bf16 = 4 MB
#define OFF_GATET  (4UL<<20)        // 16*1024*1024 bf16 = 32 MB [E][F][D]
#define OFF_UPT    (36UL<<20)       // 32 MB
#define OFF_DOWNT  (68UL<<20)       // 32 MB [E][D][F]
#define OFF_SHGT   (100UL<<20)      // [2048][1024] bf16 = 4 MB
#define OFF_SHUT   (104UL<<20)
#define OFF_SHDT   (108UL<<20)      // [1024][2048] bf16 = 4 MB
#define OFF_H      (112UL<<20)      // routed act 17.3MB, then sh_act 8MB
#define OFF_U      (132UL<<20)      // 20 MB: shared-down fp32 partials (2x8MB)
#define OFF_YSLOT  (152UL<<20)      // 20 MB
#define OFF_CTRL   (172UL<<20)
#define CT_OFFSETS  128
#define CT_NTILES   192
#define CT_TILEEXP  256
#define CT_SLOTTOK  4096
#define CT_TKSLOT   49152
#define CT_TOPKIDX  81920
#define CT_TOPKW    114688

__device__ __forceinline__ unsigned short f2bf(float f) {
  __bf16 h = (__bf16)f;
  return __builtin_bit_cast(unsigned short, h);
}
__device__ __forceinline__ float bf2f(unsigned short u) {
  unsigned int v = ((unsigned int)u) << 16;
  return __builtin_bit_cast(float, v);
}
__device__ __forceinline__ void gld16(const void* g, void* l) {
  __builtin_amdgcn_global_load_lds(
      (const __attribute__((address_space(1))) void*)(g),
      (__attribute__((address_space(3))) void*)(l), 16, 0, 0);
}

// ---- fp32 -> bf16 elementwise ----
__global__ void k_cvt(const float* __restrict__ src, unsigned short* __restrict__ dst, int n4) {
  int i = blockIdx.x * blockDim.x + threadIdx.x;
  if (i >= n4) return;
  float4 v = ((const float4*)src)[i];
  ushort4_t o;
  o[0] = f2bf(v.x); o[1] = f2bf(v.y); o[2] = f2bf(v.z); o[3] = f2bf(v.w);
  ((ushort4_t*)dst)[i] = o;
}

// ---- transpose + convert: src fp32 [R][C] -> dst bf16 [C][R] ----
__global__ void k_transpose(const float* __restrict__ src, unsigned short* __restrict__ dst,
                            int R, int C) {
  __shared__ unsigned short tile[64 * 68];
  long b = blockIdx.z;
  src += b * (long)R * C;
  dst += b * (long)R * C;
  int cT = blockIdx.x * 64, rT = blockIdx.y * 64;
  int t = threadIdx.x;
  int rb = t >> 4, cb = t & 15;
  float f[4][4];
#pragma unroll
  for (int i = 0; i < 4; i++) {
    float4 v = *(const float4*)(src + (long)(rT + 4 * rb + i) * C + cT + 4 * cb);
    f[i][0] = v.x; f[i][1] = v.y; f[i][2] = v.z; f[i][3] = v.w;
  }
#pragma unroll
  for (int j = 0; j < 4; j++) {
    ushort4_t o;
    o[0] = f2bf(f[0][j]); o[1] = f2bf(f[1][j]); o[2] = f2bf(f[2][j]); o[3] = f2bf(f[3][j]);
    int c = 4 * cb + j;
    *(ushort4_t*)&tile[c * 68 + 4 * rb] = o;
  }
  __syncthreads();
#pragma unroll
  for (int p = 0; p < 2; p++) {
    int q = t + 256 * p;
    int c = q >> 3, r0 = (q & 7) * 8;
    ushort4_t lo = *(const ushort4_t*)&tile[c * 68 + r0];
    ushort4_t hi = *(const ushort4_t*)&tile[c * 68 + r0 + 4];
    ushort8_t w8 = {lo[0], lo[1], lo[2], lo[3], hi[0], hi[1], hi[2], hi[3]};
    *(ushort8_t*)(dst + (long)(cT + c) * R + rT + r0) = w8;
  }
}

// ---- router: 1 block per token; no global atomics ----
__global__ __launch_bounds__(256) void k_router(
    const float* __restrict__ x, const float* __restrict__ rw,
    const float* __restrict__ bias, int* __restrict__ topk_idx,
    float* __restrict__ topk_w) {
  int t = blockIdx.x, tid = threadIdx.x;
  int wv = tid >> 6, lane = tid & 63;
  float4 xv = ((const float4*)(x + (size_t)t * DIM))[tid];
  float part[NEXP];
#pragma unroll
  for (int e = 0; e < NEXP; e++) {
    float4 wr = ((const float4*)(rw + (size_t)e * DIM))[tid];
    part[e] = xv.x * wr.x + xv.y * wr.y + xv.z * wr.z + xv.w * wr.w;
  }
  __shared__ float wsum_s[4 * NEXP];
#pragma unroll
  for (int e = 0; e < NEXP; e++) {
    float v = part[e];
#pragma unroll
    for (int off = 32; off; off >>= 1) v += __shfl_xor(v, off, 64);
    if (lane == 0) wsum_s[wv * NEXP + e] = v;
  }
  __syncthreads();
  if (tid == 0) {
    float r_sc[NEXP], r_s[NEXP];
#pragma unroll
    for (int e = 0; e < NEXP; e++) {
      float logit = wsum_s[e] + wsum_s[NEXP + e] + wsum_s[2 * NEXP + e] +
                    wsum_s[3 * NEXP + e];
      float sc = 1.f / (1.f + expf(-logit));
      r_sc[e] = sc;
      r_s[e] = sc + bias[e];
    }
    float gs[4];
#pragma unroll
    for (int g = 0; g < 4; g++) {
      float m1 = -1e30f, m2 = -1e30f;
#pragma unroll
      for (int j = 0; j < 4; j++) {
        float v = r_s[g * 4 + j];
        if (v > m1) { m2 = m1; m1 = v; } else if (v > m2) m2 = v;
      }
      gs[g] = m1 + m2;
    }
    int g1 = 0;
    for (int g = 1; g < 4; g++) if (gs[g] > gs[g1]) g1 = g;
    int g2 = -1;
    for (int g = 0; g < 4; g++) { if (g == g1) continue; if (g2 < 0 || gs[g] > gs[g2]) g2 = g; }
    int taken = 0, idx[4];
    float w[4], wsum = 1e-20f;
#pragma unroll
    for (int k = 0; k < 4; k++) {
      float best = -1e30f; int bi = 0;
#pragma unroll
      for (int e2 = 0; e2 < 16; e2++) {
        if (taken & (1 << e2)) continue;
        int g = e2 >> 2;
        float v = (g == g1 || g == g2) ? r_s[e2] : -1.f;
        if (v > best) { best = v; bi = e2; }
      }
      taken |= 1 << bi; idx[k] = bi;
    }
#pragma unroll
    for (int k = 0; k < 4; k++) { w[k] = r_sc[idx[k]]; wsum += w[k]; }
    float sc2 = 2.5f / wsum;
#pragma unroll
    for (int k = 0; k < 4; k++) {
      topk_idx[t * 4 + k] = idx[k];
      topk_w[t * 4 + k] = w[k] * sc2;
    }
  }
}

// ---- route_post: single block, atomic-free count + scan + scatter ----
__global__ __launch_bounds__(256) void k_route_post(
    const int* __restrict__ topk_idx, int* __restrict__ offsets,
    int* __restrict__ tile_expert, int* __restrict__ n_tiles,
    int* __restrict__ slot_token, int* __restrict__ tk_slot) {
  __shared__ int cnt[NEXP][257];
  __shared__ int offs[NEXP], tot[NEXP];
  int tid = threadIdx.x;
  int4 ent[8];
#pragma unroll
  for (int i = 0; i < 8; i++) ent[i] = ((const int4*)topk_idx)[tid * 8 + i];
  int lc[NEXP];
#pragma unroll
  for (int j = 0; j < NEXP; j++) lc[j] = 0;
#pragma unroll
  for (int i = 0; i < 8; i++) {
    int es[4] = {ent[i].x, ent[i].y, ent[i].z, ent[i].w};
#pragma unroll
    for (int k = 0; k < 4; k++)
#pragma unroll
      for (int j = 0; j < NEXP; j++) lc[j] += (es[k] == j) ? 1 : 0;
  }
#pragma unroll
  for (int j = 0; j < NEXP; j++) cnt[j][tid] = lc[j];
  __syncthreads();
  if (tid < NEXP) {
    int base = 0;
    for (int c = 0; c < 256; c += 8) {
      int v[8];
#pragma unroll
      for (int i = 0; i < 8; i++) v[i] = cnt[tid][c + i];
#pragma unroll
      for (int i = 0; i < 8; i++) { cnt[tid][c + i] = base; base += v[i]; }
    }
    tot[tid] = base;
  }
  __syncthreads();
  if (tid == 0) {
    int cum = 0, tt = 0;
    for (int e = 0; e < NEXP; e++) {
      offs[e] = cum;
      offsets[e] = cum;
      int nt = (tot[e] + 127) >> 7;
      for (int i = 0; i < nt; i++) tile_expert[tt++] = e;
      cum += nt << 7;
    }
    n_tiles[0] = tt;
  }
  __syncthreads();
  for (int e = 0; e < NEXP; e++) {
    int s0 = offs[e] + tot[e];
    int s1 = offs[e] + (((tot[e] + 127) >> 7) << 7);
    for (int s = s0 + tid; s < s1; s += 256) slot_token[s] = -1;
  }
  int lcur[NEXP];
#pragma unroll
  for (int j = 0; j < NEXP; j++) lcur[j] = offs[j] + cnt[j][tid];
#pragma unroll
  for (int i = 0; i < 8; i++) {
    int t = tid * 8 + i;
    int es[4] = {ent[i].x, ent[i].y, ent[i].z, ent[i].w};
#pragma unroll
    for (int k = 0; k < 4; k++) {
      int e = es[k], pos = 0;
#pragma unroll
      for (int j = 0; j < NEXP; j++) pos += (e == j) ? lcur[j] : 0;
#pragma unroll
      for (int j = 0; j < NEXP; j++) lcur[j] += (e == j) ? 1 : 0;
      slot_token[pos] = t;
      tk_slot[t * 4 + k] = pos;
    }
  }
}

// ---- GEMM modes ----
// MODE 0: routed gate+up+silu  grid(8, MAXTILES)   A=xb gathered, out act bf16 [slots][1024]
// MODE 1: routed down          grid(8, MAXTILES)   A=act slots,   out yslot bf16
// MODE 2: shared gate+up+silu  grid(16, 16)        A=xb direct,   out sh_act bf16 [2048][2048]
// MODE 3: shared down splitK2  grid(8, 16, 2)      A=sh_act,      out fp32 partial slabs
template <int MODE>
__global__ __launch_bounds__(256, 2) void k_gemm(
    const unsigned short* __restrict__ Abase, const unsigned short* __restrict__ B0,
    const unsigned short* __restrict__ B1, unsigned short* __restrict__ O0,
    float* __restrict__ OF,
    const int* __restrict__ slot_token, const int* __restrict__ tile_expert,
    const int* __restrict__ n_tiles) {
  constexpr bool FUSED = (MODE == 0 || MODE == 2);
  constexpr int KT = (MODE == 3) ? 32 : 32;           // k-iters (MODE 3: per slab)
  constexpr int AW = (MODE == 3) ? 2048 : 1024;       // A row stride (shorts)
  constexpr int BW = (MODE == 3) ? 2048 : 1024;       // B row stride (shorts)
  constexpr int OW = (MODE == 2) ? 2048 : 1024;       // out row stride

  int nx = blockIdx.x, bt = blockIdx.y;
  if (MODE == 0 || MODE == 1) { if (bt >= n_tiles[0]) return; }
  int n0 = nx * 128;
  const unsigned short *Bg, *Bu = nullptr;
  if (MODE == 0) { int e = tile_expert[bt]; Bg = B0 + (size_t)e * 1024 * 1024; Bu = B1 + (size_t)e * 1024 * 1024; }
  else if (MODE == 1) { int e = tile_expert[bt]; Bg = B0 + (size_t)e * 1024 * 1024; }
  else if (MODE == 2) { Bg = B0; Bu = B1; }
  else { Bg = B0; }

  __shared__ unsigned short sA[128 * 32];
  __shared__ unsigned short sBg[128 * 32];
  __shared__ unsigned short sBu[FUSED ? 128 * 32 : 1];

  int tid = threadIdx.x;
  int w = tid >> 6, L = tid & 63;
  int c0 = w * 128 + L, c1 = c0 + 64;
  int ar0 = c0 >> 2, ar1 = c1 >> 2;
  int ch0 = (c0 & 3) ^ (ar0 & 3), ch1 = (c1 & 3) ^ (ar1 & 3);  // xor-swizzle
  long arow0, arow1;
  if (MODE == 0) {
    int t0 = slot_token[bt * 128 + ar0]; if (t0 < 0) t0 = 0;
    int t1 = slot_token[bt * 128 + ar1]; if (t1 < 0) t1 = 0;
    arow0 = t0; arow1 = t1;
  } else {
    arow0 = bt * 128 + ar0; arow1 = bt * 128 + ar1;
  }
  long kbase = (MODE == 3) ? (long)blockIdx.z * 1024 : 0;
  const char* aA = (const char*)(Abase + arow0 * AW + kbase) + ch0 * 16;
  const char* aB = (const char*)(Abase + arow1 * AW + kbase) + ch1 * 16;
  const char* gA = (const char*)(Bg + (size_t)(n0 + ar0) * BW + kbase) + ch0 * 16;
  const char* gB = (const char*)(Bg + (size_t)(n0 + ar1) * BW + kbase) + ch1 * 16;
  const char* uA = FUSED ? (const char*)(Bu + (size_t)(n0 + ar0) * BW) + ch0 * 16 : nullptr;
  const char* uB = FUSED ? (const char*)(Bu + (size_t)(n0 + ar1) * BW) + ch1 * 16 : nullptr;
  char* dA0 = (char*)sA + (w * 128) * 16;
  char* dA1 = (char*)sA + (w * 128 + 64) * 16;
  char* dG0 = (char*)sBg + (w * 128) * 16;
  char* dG1 = (char*)sBg + (w * 128 + 64) * 16;
  char* dU0 = (char*)sBu + (w * 128) * 16;
  char* dU1 = (char*)sBu + (w * 128 + 64) * 16;

  f32x4_t accg[4][4], accu[4][4];
#pragma unroll
  for (int i = 0; i < 4; i++)
#pragma unroll
    for (int j = 0; j < 4; j++) {
      accg[i][j] = f32x4_t{0.f, 0.f, 0.f, 0.f};
      if (FUSED) accu[i][j] = f32x4_t{0.f, 0.f, 0.f, 0.f};
    }

  int mb = (w >> 1) * 64, nb = (w & 1) * 64;
  int lr = L & 15, quad = L >> 4;
  int sw = ((quad ^ (lr & 3)) << 3);  // swizzled chunk offset (shorts), loop-invariant

  for (int kt = 0; kt < KT; ++kt) {
    gld16(aA, dA0); gld16(aB, dA1);
    gld16(gA, dG0); gld16(gB, dG1);
    if (FUSED) { gld16(uA, dU0); gld16(uB, dU1); }
    aA += 64; aB += 64; gA += 64; gB += 64;
    if (FUSED) { uA += 64; uB += 64; }
    __syncthreads();
    bf16x8_t af[4], bg[4], bu[4];
#pragma unroll
    for (int i = 0; i < 4; i++) af[i] = *(const bf16x8_t*)(sA + (mb + 16 * i + lr) * 32 + sw);
#pragma unroll
    for (int i = 0; i < 4; i++) bg[i] = *(const bf16x8_t*)(sBg + (nb + 16 * i + lr) * 32 + sw);
    if (FUSED) {
#pragma unroll
      for (int i = 0; i < 4; i++) bu[i] = *(const bf16x8_t*)(sBu + (nb + 16 * i + lr) * 32 + sw);
    }
#pragma unroll
    for (int i = 0; i < 4; i++)
#pragma unroll
      for (int j = 0; j < 4; j++) {
        accg[i][j] = __builtin_amdgcn_mfma_f32_16x16x32_bf16(af[i], bg[j], accg[i][j], 0, 0, 0);
        if (FUSED)
          accu[i][j] = __builtin_amdgcn_mfma_f32_16x16x32_bf16(af[i], bu[j], accu[i][j], 0, 0, 0);
      }
    __syncthreads();
  }

#pragma unroll
  for (int i = 0; i < 4; i++) {
    int rowb = bt * 128 + mb + 16 * i + quad * 4;
#pragma unroll
    for (int j = 0; j < 4; j++) {
      int col = n0 + nb + 16 * j + lr;
#pragma unroll
      for (int r = 0; r < 4; r++) {
        float h = accg[i][j][r];
        if (FUSED) {
          float u = accu[i][j][r];
          float act = h / (1.f + __expf(-h)) * u;
          O0[(size_t)(rowb + r) * OW + col] = f2bf(act);
        } else if (MODE == 1) {
          O0[(size_t)(rowb + r) * OW + col] = f2bf(h);
        } else {  // MODE 3: fp32 partial slab
          OF[(size_t)blockIdx.z * (T_TOK * 1024) + (size_t)(rowb + r) * 1024 + col] = h;
        }
      }
    }
  }
}

// ---- final gather: out = shared(p0+p1) + sum_k w_k * yslot ----
__global__ void k_gather(float* __restrict__ out, const float* __restrict__ partial,
                         const unsigned short* __restrict__ yslot,
                         const int* __restrict__ tk_slot, const float* __restrict__ topk_w) {
  int t = blockIdx.x, tid = threadIdx.x;
  int4 sl = ((const int4*)tk_slot)[t];
  float4 wv = ((const float4*)topk_w)[t];
  int d = 4 * tid;
  float4 p0 = *(const float4*)(partial + (size_t)t * 1024 + d);
  float4 p1 = *(const float4*)(partial + (size_t)(T_TOK * 1024) + (size_t)t * 1024 + d);
  float4 o = {p0.x + p1.x, p0.y + p1.y, p0.z + p1.z, p0.w + p1.w};
  const int s[4] = {sl.x, sl.y, sl.z, sl.w};
  const float wk[4] = {wv.x, wv.y, wv.z, wv.w};
#pragma unroll
  for (int k = 0; k < 4; k++) {
    ushort4_t y = *(const ushort4_t*)(yslot + (size_t)s[k] * 1024 + d);
    o.x += wk[k] * bf2f(y[0]);
    o.y += wk[k] * bf2f(y[1]);
    o.z += wk[k] * bf2f(y[2]);
    o.w += wk[k] * bf2f(y[3]);
  }
  *(float4*)(out + (size_t)t * 1024 + d) = o;
}

extern "C" void kernel_launch(void* const* d_in, const int* in_sizes, int n_in,
                              void* d_out, int out_size, void* d_ws, size_t ws_size,
                              hipStream_t stream) {
  const float* x = (const float*)d_in[0];
  const float* rw = (const float*)d_in[1];
  const float* bias = (const float*)d_in[2];
  const float* gw = (const float*)d_in[3];
  const float* uw = (const float*)d_in[4];
  const float* dw = (const float*)d_in[5];
  const float* sg = (const float*)d_in[6];
  const float* su = (const float*)d_in[7];
  const float* sd = (const float*)d_in[8];
  float* out = (float*)d_out;
  char* ws = (char*)d_ws;

  unsigned short* xb    = (unsigned short*)(ws + OFF_XB);
  unsigned short* gateT = (unsigned short*)(ws + OFF_GATET);
  unsigned short* upT   = (unsigned short*)(ws + OFF_UPT);
  unsigned short* downT = (unsigned short*)(ws + OFF_DOWNT);
  unsigned short* shGT  = (unsigned short*)(ws + OFF_SHGT);
  unsigned short* shUT  = (unsigned short*)(ws + OFF_SHUT);
  unsigned short* shDT  = (unsigned short*)(ws + OFF_SHDT);
  unsigned short* Hbuf  = (unsigned short*)(ws + OFF_H);     // routed act, then sh_act
  float*          part  = (float*)(ws + OFF_U);              // shared-down partials
  unsigned short* yslot = (unsigned short*)(ws + OFF_YSLOT);
  char* ctrl = ws + OFF_CTRL;
  int* offsets_    = (int*)(ctrl + CT_OFFSETS);
  int* n_tiles     = (int*)(ctrl + CT_NTILES);
  int* tile_expert = (int*)(ctrl + CT_TILEEXP);
  int* slot_token  = (int*)(ctrl + CT_SLOTTOK);
  int* tk_slot     = (int*)(ctrl + CT_TKSLOT);
  int* topk_idx    = (int*)(ctrl + CT_TOPKIDX);
  float* topk_w    = (float*)(ctrl + CT_TOPKW);

  k_cvt<<<2048, 256, 0, stream>>>(x, xb, T_TOK * DIM / 4);
  k_transpose<<<dim3(16, 16, 16), 256, 0, stream>>>(gw, gateT, 1024, 1024);
  k_transpose<<<dim3(16, 16, 16), 256, 0, stream>>>(uw, upT, 1024, 1024);
  k_transpose<<<dim3(16, 16, 16), 256, 0, stream>>>(dw, downT, 1024, 1024);
  k_transpose<<<dim3(32, 16, 1), 256, 0, stream>>>(sg, shGT, 1024, 2048);
  k_transpose<<<dim3(32, 16, 1), 256, 0, stream>>>(su, shUT, 1024, 2048);
  k_transpose<<<dim3(16, 32, 1), 256, 0, stream>>>(sd, shDT, 2048, 1024);
  k_router<<<2048, 256, 0, stream>>>(x, rw, bias, topk_idx, topk_w);
  k_route_post<<<1, 256, 0, stream>>>(topk_idx, offsets_, tile_expert, n_tiles,
                                      slot_token, tk_slot);
  // routed gate+up+silu -> act (Hbuf)
  k_gemm<0><<<dim3(8, MAXTILES), 256, 0, stream>>>(xb, gateT, upT, Hbuf, nullptr,
                                                   slot_token, tile_expert, n_tiles);
  // routed down -> yslot
  k_gemm<1><<<dim3(8, MAXTILES), 256, 0, stream>>>(Hbuf, downT, nullptr, yslot, nullptr,
                                                   slot_token, tile_expert, n_tiles);
  // shared gate+up+silu -> sh_act (Hbuf, after gemm1 consumed routed act)
  k_gemm<2><<<dim3(16, 16), 256, 0, stream>>>(xb, shGT, shUT, Hbuf, nullptr,
                                              slot_token, tile_expert, n_tiles);
  // shared down, split-K=2 -> fp32 partial slabs
  k_gemm<3><<<dim3(8, 16, 2), 256, 0, stream>>>(Hbuf, shDT, nullptr, nullptr, part,
                                                slot_token, tile_expert, n_tiles);
  // out = p0+p1 + weighted routed
  k_gather<<<2048, 256, 0, stream>>>(out, part, yslot, tk_slot, topk_w);
}

// Round 5
// 433.051 us; speedup vs baseline: 1.3379x; 1.0976x over previous
//
#include <hip/hip_runtime.h>
#include <cstdint>
#include <cstddef>

// DeepseekV3 MoE on gfx950.
// R4->R5: UNIFIED expert pipeline. Shared experts = 2 extra F=1024 experts
// (sh_gate [D,2048] splits at f=1024; sh_down splits as two K-halves whose
// outputs sum). One fused gate+up+silu GEMM covers 112 tiles (<=80 routed +
// 32 shared) x 8 n-tiles = 896 blocks (3.5/CU vs 640+256 split before), one
// down GEMM likewise. Removes 2 GEMM launches (256-block 1/CU stragglers).
// R4 lesson: fused kernel was latency-bound (12% HBM, 18.5% MfmaUtil, 13%
// occupancy) -> more co-resident blocks is the lever. Shared-down stays fp32
// partials for precision. Partials overlay dead xb/shGT/shUT region.

#define T_TOK 2048
#define DIM   1024
#define NEXP  16
#define MAXTILES 80
#define SH_TILES 32
#define GRID_Y (MAXTILES + SH_TILES)
#define ABASE_SH 10240   // act row where shared-expert rows start

typedef __bf16 bf16x8_t __attribute__((ext_vector_type(8)));
typedef float  f32x4_t  __attribute__((ext_vector_type(4)));
typedef unsigned short ushort8_t __attribute__((ext_vector_type(8)));
typedef unsigned short ushort4_t __attribute__((ext_vector_type(4)));

// ---- workspace layout (bytes) ----
#define OFF_XB     (0UL)            // 4 MB   (dead after k_gateup)
#define OFF_SHGT   (4UL<<20)        // 4 MB   [2048][1024] (dead after k_gateup)
#define OFF_SHUT   (8UL<<20)        // 4 MB
#define OFF_GATET  (12UL<<20)       // 32 MB  [E][F][D]
#define OFF_UPT    (44UL<<20)       // 32 MB
#define OFF_DOWNT  (76UL<<20)       // 32 MB  [E][D][F]
#define OFF_SHDT   (108UL<<20)      // 4 MB   [1024][2048]
#define OFF_ACT    (112UL<<20)      // 28 MB  (14336 rows x 1024 bf16)
#define OFF_YSLOT  (140UL<<20)      // 20 MB  (10240 rows x 1024 bf16)
#define OFF_PART   (0UL)            // 16 MB  fp32 2 slabs, overlays XB/SHGT/SHUT
#define OFF_CTRL   (160UL<<20)
#define CT_OFFSETS  128
#define CT_NTILES   192
#define CT_TILEEXP  256
#define CT_SLOTTOK  4096
#define CT_TKSLOT   49152
#define CT_TOPKIDX  81920
#define CT_TOPKW    114688

__device__ __forceinline__ unsigned short f2bf(float f) {
  __bf16 h = (__bf16)f;
  return __builtin_bit_cast(unsigned short, h);
}
__device__ __forceinline__ float bf2f(unsigned short u) {
  unsigned int v = ((unsigned int)u) << 16;
  return __builtin_bit_cast(float, v);
}
__device__ __forceinline__ void gld16(const void* g, void* l) {
  __builtin_amdgcn_global_load_lds(
      (const __attribute__((address_space(1))) void*)(g),
      (__attribute__((address_space(3))) void*)(l), 16, 0, 0);
}

// ---- fp32 -> bf16 elementwise ----
__global__ void k_cvt(const float* __restrict__ src, unsigned short* __restrict__ dst, int n4) {
  int i = blockIdx.x * blockDim.x + threadIdx.x;
  if (i >= n4) return;
  float4 v = ((const float4*)src)[i];
  ushort4_t o;
  o[0] = f2bf(v.x); o[1] = f2bf(v.y); o[2] = f2bf(v.z); o[3] = f2bf(v.w);
  ((ushort4_t*)dst)[i] = o;
}

// ---- transpose + convert: src fp32 [R][C] -> dst bf16 [C][R] ----
__global__ void k_transpose(const float* __restrict__ src, unsigned short* __restrict__ dst,
                            int R, int C) {
  __shared__ unsigned short tile[64 * 68];
  long b = blockIdx.z;
  src += b * (long)R * C;
  dst += b * (long)R * C;
  int cT = blockIdx.x * 64, rT = blockIdx.y * 64;
  int t = threadIdx.x;
  int rb = t >> 4, cb = t & 15;
  float f[4][4];
#pragma unroll
  for (int i = 0; i < 4; i++) {
    float4 v = *(const float4*)(src + (long)(rT + 4 * rb + i) * C + cT + 4 * cb);
    f[i][0] = v.x; f[i][1] = v.y; f[i][2] = v.z; f[i][3] = v.w;
  }
#pragma unroll
  for (int j = 0; j < 4; j++) {
    ushort4_t o;
    o[0] = f2bf(f[0][j]); o[1] = f2bf(f[1][j]); o[2] = f2bf(f[2][j]); o[3] = f2bf(f[3][j]);
    int c = 4 * cb + j;
    *(ushort4_t*)&tile[c * 68 + 4 * rb] = o;
  }
  __syncthreads();
#pragma unroll
  for (int p = 0; p < 2; p++) {
    int q = t + 256 * p;
    int c = q >> 3, r0 = (q & 7) * 8;
    ushort4_t lo = *(const ushort4_t*)&tile[c * 68 + r0];
    ushort4_t hi = *(const ushort4_t*)&tile[c * 68 + r0 + 4];
    ushort8_t w8 = {lo[0], lo[1], lo[2], lo[3], hi[0], hi[1], hi[2], hi[3]};
    *(ushort8_t*)(dst + (long)(cT + c) * R + rT + r0) = w8;
  }
}

// ---- router: 1 block per token; no global atomics ----
__global__ __launch_bounds__(256) void k_router(
    const float* __restrict__ x, const float* __restrict__ rw,
    const float* __restrict__ bias, int* __restrict__ topk_idx,
    float* __restrict__ topk_w) {
  int t = blockIdx.x, tid = threadIdx.x;
  int wv = tid >> 6, lane = tid & 63;
  float4 xv = ((const float4*)(x + (size_t)t * DIM))[tid];
  float part[NEXP];
#pragma unroll
  for (int e = 0; e < NEXP; e++) {
    float4 wr = ((const float4*)(rw + (size_t)e * DIM))[tid];
    part[e] = xv.x * wr.x + xv.y * wr.y + xv.z * wr.z + xv.w * wr.w;
  }
  __shared__ float wsum_s[4 * NEXP];
#pragma unroll
  for (int e = 0; e < NEXP; e++) {
    float v = part[e];
#pragma unroll
    for (int off = 32; off; off >>= 1) v += __shfl_xor(v, off, 64);
    if (lane == 0) wsum_s[wv * NEXP + e] = v;
  }
  __syncthreads();
  if (tid == 0) {
    float r_sc[NEXP], r_s[NEXP];
#pragma unroll
    for (int e = 0; e < NEXP; e++) {
      float logit = wsum_s[e] + wsum_s[NEXP + e] + wsum_s[2 * NEXP + e] +
                    wsum_s[3 * NEXP + e];
      float sc = 1.f / (1.f + expf(-logit));
      r_sc[e] = sc;
      r_s[e] = sc + bias[e];
    }
    float gs[4];
#pragma unroll
    for (int g = 0; g < 4; g++) {
      float m1 = -1e30f, m2 = -1e30f;
#pragma unroll
      for (int j = 0; j < 4; j++) {
        float v = r_s[g * 4 + j];
        if (v > m1) { m2 = m1; m1 = v; } else if (v > m2) m2 = v;
      }
      gs[g] = m1 + m2;
    }
    int g1 = 0;
    for (int g = 1; g < 4; g++) if (gs[g] > gs[g1]) g1 = g;
    int g2 = -1;
    for (int g = 0; g < 4; g++) { if (g == g1) continue; if (g2 < 0 || gs[g] > gs[g2]) g2 = g; }
    int taken = 0, idx[4];
    float w[4], wsum = 1e-20f;
#pragma unroll
    for (int k = 0; k < 4; k++) {
      float best = -1e30f; int bi = 0;
#pragma unroll
      for (int e2 = 0; e2 < 16; e2++) {
        if (taken & (1 << e2)) continue;
        int g = e2 >> 2;
        float v = (g == g1 || g == g2) ? r_s[e2] : -1.f;
        if (v > best) { best = v; bi = e2; }
      }
      taken |= 1 << bi; idx[k] = bi;
    }
#pragma unroll
    for (int k = 0; k < 4; k++) { w[k] = r_sc[idx[k]]; wsum += w[k]; }
    float sc2 = 2.5f / wsum;
#pragma unroll
    for (int k = 0; k < 4; k++) {
      topk_idx[t * 4 + k] = idx[k];
      topk_w[t * 4 + k] = w[k] * sc2;
    }
  }
}

// ---- route_post: single block, atomic-free count + scan + scatter ----
__global__ __launch_bounds__(256) void k_route_post(
    const int* __restrict__ topk_idx, int* __restrict__ offsets,
    int* __restrict__ tile_expert, int* __restrict__ n_tiles,
    int* __restrict__ slot_token, int* __restrict__ tk_slot) {
  __shared__ int cnt[NEXP][257];
  __shared__ int offs[NEXP], tot[NEXP];
  int tid = threadIdx.x;
  int4 ent[8];
#pragma unroll
  for (int i = 0; i < 8; i++) ent[i] = ((const int4*)topk_idx)[tid * 8 + i];
  int lc[NEXP];
#pragma unroll
  for (int j = 0; j < NEXP; j++) lc[j] = 0;
#pragma unroll
  for (int i = 0; i < 8; i++) {
    int es[4] = {ent[i].x, ent[i].y, ent[i].z, ent[i].w};
#pragma unroll
    for (int k = 0; k < 4; k++)
#pragma unroll
      for (int j = 0; j < NEXP; j++) lc[j] += (es[k] == j) ? 1 : 0;
  }
#pragma unroll
  for (int j = 0; j < NEXP; j++) cnt[j][tid] = lc[j];
  __syncthreads();
  if (tid < NEXP) {
    int base = 0;
    for (int c = 0; c < 256; c += 8) {
      int v[8];
#pragma unroll
      for (int i = 0; i < 8; i++) v[i] = cnt[tid][c + i];
#pragma unroll
      for (int i = 0; i < 8; i++) { cnt[tid][c + i] = base; base += v[i]; }
    }
    tot[tid] = base;
  }
  __syncthreads();
  if (tid == 0) {
    int cum = 0, tt = 0;
    for (int e = 0; e < NEXP; e++) {
      offs[e] = cum;
      offsets[e] = cum;
      int nt = (tot[e] + 127) >> 7;
      for (int i = 0; i < nt; i++) tile_expert[tt++] = e;
      cum += nt << 7;
    }
    n_tiles[0] = tt;
  }
  __syncthreads();
  for (int e = 0; e < NEXP; e++) {
    int s0 = offs[e] + tot[e];
    int s1 = offs[e] + (((tot[e] + 127) >> 7) << 7);
    for (int s = s0 + tid; s < s1; s += 256) slot_token[s] = -1;
  }
  int lcur[NEXP];
#pragma unroll
  for (int j = 0; j < NEXP; j++) lcur[j] = offs[j] + cnt[j][tid];
#pragma unroll
  for (int i = 0; i < 8; i++) {
    int t = tid * 8 + i;
    int es[4] = {ent[i].x, ent[i].y, ent[i].z, ent[i].w};
#pragma unroll
    for (int k = 0; k < 4; k++) {
      int e = es[k], pos = 0;
#pragma unroll
      for (int j = 0; j < NEXP; j++) pos += (e == j) ? lcur[j] : 0;
#pragma unroll
      for (int j = 0; j < NEXP; j++) lcur[j] += (e == j) ? 1 : 0;
      slot_token[pos] = t;
      tk_slot[t * 4 + k] = pos;
    }
  }
}

// ---- fused gate+up+silu GEMM, unified routed+shared ----
// grid (8, 112). bt < NT: routed tile (A rows gathered via slot_token,
// B = per-expert gate/up, act rows = slots). NT <= bt < NT+32: shared tile
// st = bt-NT, expert se = st>>4, token-tile tt = st&15 (A rows = tokens,
// B = shGT/shUT + se*1M, act rows = ABASE_SH + se*2048 + tokens).
__global__ __launch_bounds__(256, 2) void k_gateup(
    const unsigned short* __restrict__ xb, const unsigned short* __restrict__ gateT,
    const unsigned short* __restrict__ upT, const unsigned short* __restrict__ shGT,
    const unsigned short* __restrict__ shUT, unsigned short* __restrict__ act,
    const int* __restrict__ slot_token, const int* __restrict__ tile_expert,
    const int* __restrict__ n_tiles) {
  int nx = blockIdx.x, bt = blockIdx.y;
  int NT = n_tiles[0];
  bool routed = bt < NT;
  const unsigned short *Bg, *Bu;
  int actbase, tokbase = 0;
  if (routed) {
    int e = tile_expert[bt];
    Bg = gateT + ((size_t)e << 20);
    Bu = upT + ((size_t)e << 20);
    actbase = bt * 128;
  } else {
    int st = bt - NT;
    if (st >= SH_TILES) return;
    int se = st >> 4, tt = st & 15;
    Bg = shGT + ((size_t)se << 20);
    Bu = shUT + ((size_t)se << 20);
    actbase = ABASE_SH + se * T_TOK + tt * 128;
    tokbase = tt * 128;
  }
  int n0 = nx * 128;

  __shared__ unsigned short sA[128 * 32];
  __shared__ unsigned short sBg[128 * 32];
  __shared__ unsigned short sBu[128 * 32];

  int tid = threadIdx.x;
  int w = tid >> 6, L = tid & 63;
  int c0 = w * 128 + L, c1 = c0 + 64;
  int ar0 = c0 >> 2, ar1 = c1 >> 2;
  int ch0 = (c0 & 3) ^ (ar0 & 3), ch1 = (c1 & 3) ^ (ar1 & 3);
  long arow0, arow1;
  if (routed) {
    int t0 = slot_token[bt * 128 + ar0]; if (t0 < 0) t0 = 0;
    int t1 = slot_token[bt * 128 + ar1]; if (t1 < 0) t1 = 0;
    arow0 = t0; arow1 = t1;
  } else {
    arow0 = tokbase + ar0; arow1 = tokbase + ar1;
  }
  const char* aA = (const char*)(xb + arow0 * 1024) + ch0 * 16;
  const char* aB = (const char*)(xb + arow1 * 1024) + ch1 * 16;
  const char* gA = (const char*)(Bg + (size_t)(n0 + ar0) * 1024) + ch0 * 16;
  const char* gB = (const char*)(Bg + (size_t)(n0 + ar1) * 1024) + ch1 * 16;
  const char* uA = (const char*)(Bu + (size_t)(n0 + ar0) * 1024) + ch0 * 16;
  const char* uB = (const char*)(Bu + (size_t)(n0 + ar1) * 1024) + ch1 * 16;
  char* dA0 = (char*)sA + (w * 128) * 16;
  char* dA1 = (char*)sA + (w * 128 + 64) * 16;
  char* dG0 = (char*)sBg + (w * 128) * 16;
  char* dG1 = (char*)sBg + (w * 128 + 64) * 16;
  char* dU0 = (char*)sBu + (w * 128) * 16;
  char* dU1 = (char*)sBu + (w * 128 + 64) * 16;

  f32x4_t accg[4][4], accu[4][4];
#pragma unroll
  for (int i = 0; i < 4; i++)
#pragma unroll
    for (int j = 0; j < 4; j++) {
      accg[i][j] = f32x4_t{0.f, 0.f, 0.f, 0.f};
      accu[i][j] = f32x4_t{0.f, 0.f, 0.f, 0.f};
    }

  int mb = (w >> 1) * 64, nb = (w & 1) * 64;
  int lr = L & 15, quad = L >> 4;
  int sw = ((quad ^ (lr & 3)) << 3);

  for (int kt = 0; kt < 32; ++kt) {
    gld16(aA, dA0); gld16(aB, dA1);
    gld16(gA, dG0); gld16(gB, dG1);
    gld16(uA, dU0); gld16(uB, dU1);
    aA += 64; aB += 64; gA += 64; gB += 64; uA += 64; uB += 64;
    __syncthreads();
    bf16x8_t af[4], bg[4], bu[4];
#pragma unroll
    for (int i = 0; i < 4; i++) af[i] = *(const bf16x8_t*)(sA + (mb + 16 * i + lr) * 32 + sw);
#pragma unroll
    for (int i = 0; i < 4; i++) bg[i] = *(const bf16x8_t*)(sBg + (nb + 16 * i + lr) * 32 + sw);
#pragma unroll
    for (int i = 0; i < 4; i++) bu[i] = *(const bf16x8_t*)(sBu + (nb + 16 * i + lr) * 32 + sw);
#pragma unroll
    for (int i = 0; i < 4; i++)
#pragma unroll
      for (int j = 0; j < 4; j++) {
        accg[i][j] = __builtin_amdgcn_mfma_f32_16x16x32_bf16(af[i], bg[j], accg[i][j], 0, 0, 0);
        accu[i][j] = __builtin_amdgcn_mfma_f32_16x16x32_bf16(af[i], bu[j], accu[i][j], 0, 0, 0);
      }
    __syncthreads();
  }

#pragma unroll
  for (int i = 0; i < 4; i++) {
    int rowb = actbase + mb + 16 * i + quad * 4;
#pragma unroll
    for (int j = 0; j < 4; j++) {
      int col = n0 + nb + 16 * j + lr;
#pragma unroll
      for (int r = 0; r < 4; r++) {
        float h = accg[i][j][r];
        float u = accu[i][j][r];
        float a = h / (1.f + __expf(-h)) * u;
        act[(size_t)(rowb + r) * 1024 + col] = f2bf(a);
      }
    }
  }
}

// ---- down GEMM, unified routed+shared ----
// routed: A = act slots, B = downT[e] (stride 1024), out yslot bf16.
// shared: A = act shared rows, B = shDT + se*1024 (stride 2048),
//         out fp32 partial slab se.
__global__ __launch_bounds__(256, 2) void k_down(
    const unsigned short* __restrict__ act, const unsigned short* __restrict__ downT,
    const unsigned short* __restrict__ shDT, unsigned short* __restrict__ yslot,
    float* __restrict__ part, const int* __restrict__ tile_expert,
    const int* __restrict__ n_tiles) {
  int nx = blockIdx.x, bt = blockIdx.y;
  int NT = n_tiles[0];
  bool routed = bt < NT;
  const unsigned short* B;
  size_t bstride;
  int abase, obase, se = 0;
  if (routed) {
    int e = tile_expert[bt];
    B = downT + ((size_t)e << 20);
    bstride = 1024;
    abase = bt * 128;
    obase = bt * 128;
  } else {
    int st = bt - NT;
    if (st >= SH_TILES) return;
    se = st >> 4;
    int tt = st & 15;
    B = shDT + se * 1024;
    bstride = 2048;
    abase = ABASE_SH + se * T_TOK + tt * 128;
    obase = tt * 128;
  }
  int n0 = nx * 128;

  __shared__ unsigned short sA[128 * 32];
  __shared__ unsigned short sB[128 * 32];

  int tid = threadIdx.x;
  int w = tid >> 6, L = tid & 63;
  int c0 = w * 128 + L, c1 = c0 + 64;
  int ar0 = c0 >> 2, ar1 = c1 >> 2;
  int ch0 = (c0 & 3) ^ (ar0 & 3), ch1 = (c1 & 3) ^ (ar1 & 3);
  const char* aA = (const char*)(act + (size_t)(abase + ar0) * 1024) + ch0 * 16;
  const char* aB = (const char*)(act + (size_t)(abase + ar1) * 1024) + ch1 * 16;
  const char* bA = (const char*)(B + (size_t)(n0 + ar0) * bstride) + ch0 * 16;
  const char* bB = (const char*)(B + (size_t)(n0 + ar1) * bstride) + ch1 * 16;
  char* dA0 = (char*)sA + (w * 128) * 16;
  char* dA1 = (char*)sA + (w * 128 + 64) * 16;
  char* dB0 = (char*)sB + (w * 128) * 16;
  char* dB1 = (char*)sB + (w * 128 + 64) * 16;

  f32x4_t acc[4][4];
#pragma unroll
  for (int i = 0; i < 4; i++)
#pragma unroll
    for (int j = 0; j < 4; j++) acc[i][j] = f32x4_t{0.f, 0.f, 0.f, 0.f};

  int mb = (w >> 1) * 64, nb = (w & 1) * 64;
  int lr = L & 15, quad = L >> 4;
  int sw = ((quad ^ (lr & 3)) << 3);

  for (int kt = 0; kt < 32; ++kt) {
    gld16(aA, dA0); gld16(aB, dA1);
    gld16(bA, dB0); gld16(bB, dB1);
    aA += 64; aB += 64; bA += 64; bB += 64;
    __syncthreads();
    bf16x8_t af[4], bf[4];
#pragma unroll
    for (int i = 0; i < 4; i++) af[i] = *(const bf16x8_t*)(sA + (mb + 16 * i + lr) * 32 + sw);
#pragma unroll
    for (int i = 0; i < 4; i++) bf[i] = *(const bf16x8_t*)(sB + (nb + 16 * i + lr) * 32 + sw);
#pragma unroll
    for (int i = 0; i < 4; i++)
#pragma unroll
      for (int j = 0; j < 4; j++)
        acc[i][j] = __builtin_amdgcn_mfma_f32_16x16x32_bf16(af[i], bf[j], acc[i][j], 0, 0, 0);
    __syncthreads();
  }

#pragma unroll
  for (int i = 0; i < 4; i++) {
    int rowb = obase + mb + 16 * i + quad * 4;
#pragma unroll
    for (int j = 0; j < 4; j++) {
      int col = n0 + nb + 16 * j + lr;
#pragma unroll
      for (int r = 0; r < 4; r++) {
        float v = acc[i][j][r];
        if (routed) yslot[(size_t)(rowb + r) * 1024 + col] = f2bf(v);
        else part[(size_t)se * (T_TOK * 1024) + (size_t)(rowb + r) * 1024 + col] = v;
      }
    }
  }
}

// ---- final gather: out = part0 + part1 + sum_k w_k * yslot[slot_k] ----
__global__ void k_gather(float* __restrict__ out, const float* __restrict__ partial,
                         const unsigned short* __restrict__ yslot,
                         const int* __restrict__ tk_slot, const float* __restrict__ topk_w) {
  int t = blockIdx.x, tid = threadIdx.x;
  int4 sl = ((const int4*)tk_slot)[t];
  float4 wv = ((const float4*)topk_w)[t];
  int d = 4 * tid;
  float4 p0 = *(const float4*)(partial + (size_t)t * 1024 + d);
  float4 p1 = *(const float4*)(partial + (size_t)(T_TOK * 1024) + (size_t)t * 1024 + d);
  float4 o = {p0.x + p1.x, p0.y + p1.y, p0.z + p1.z, p0.w + p1.w};
  const int s[4] = {sl.x, sl.y, sl.z, sl.w};
  const float wk[4] = {wv.x, wv.y, wv.z, wv.w};
#pragma unroll
  for (int k = 0; k < 4; k++) {
    ushort4_t y = *(const ushort4_t*)(yslot + (size_t)s[k] * 1024 + d);
    o.x += wk[k] * bf2f(y[0]);
    o.y += wk[k] * bf2f(y[1]);
    o.z += wk[k] * bf2f(y[2]);
    o.w += wk[k] * bf2f(y[3]);
  }
  *(float4*)(out + (size_t)t * 1024 + d) = o;
}

extern "C" void kernel_launch(void* const* d_in, const int* in_sizes, int n_in,
                              void* d_out, int out_size, void* d_ws, size_t ws_size,
                              hipStream_t stream) {
  const float* x = (const float*)d_in[0];
  const float* rw = (const float*)d_in[1];
  const float* bias = (const float*)d_in[2];
  const float* gw = (const float*)d_in[3];
  const float* uw = (const float*)d_in[4];
  const float* dw = (const float*)d_in[5];
  const float* sg = (const float*)d_in[6];
  const float* su = (const float*)d_in[7];
  const float* sd = (const float*)d_in[8];
  float* out = (float*)d_out;
  char* ws = (char*)d_ws;

  unsigned short* xb    = (unsigned short*)(ws + OFF_XB);
  unsigned short* shGT  = (unsigned short*)(ws + OFF_SHGT);
  unsigned short* shUT  = (unsigned short*)(ws + OFF_SHUT);
  unsigned short* gateT = (unsigned short*)(ws + OFF_GATET);
  unsigned short* upT   = (unsigned short*)(ws + OFF_UPT);
  unsigned short* downT = (unsigned short*)(ws + OFF_DOWNT);
  unsigned short* shDT  = (unsigned short*)(ws + OFF_SHDT);
  unsigned short* act   = (unsigned short*)(ws + OFF_ACT);
  unsigned short* yslot = (unsigned short*)(ws + OFF_YSLOT);
  float*          part  = (float*)(ws + OFF_PART);   // overlays xb/shGT/shUT
  char* ctrl = ws + OFF_CTRL;
  int* offsets_    = (int*)(ctrl + CT_OFFSETS);
  int* n_tiles     = (int*)(ctrl + CT_NTILES);
  int* tile_expert = (int*)(ctrl + CT_TILEEXP);
  int* slot_token  = (int*)(ctrl + CT_SLOTTOK);
  int* tk_slot     = (int*)(ctrl + CT_TKSLOT);
  int* topk_idx    = (int*)(ctrl + CT_TOPKIDX);
  float* topk_w    = (float*)(ctrl + CT_TOPKW);

  k_cvt<<<2048, 256, 0, stream>>>(x, xb, T_TOK * DIM / 4);
  k_transpose<<<dim3(16, 16, 16), 256, 0, stream>>>(gw, gateT, 1024, 1024);
  k_transpose<<<dim3(16, 16, 16), 256, 0, stream>>>(uw, upT, 1024, 1024);
  k_transpose<<<dim3(16, 16, 16), 256, 0, stream>>>(dw, downT, 1024, 1024);
  k_transpose<<<dim3(32, 16, 1), 256, 0, stream>>>(sg, shGT, 1024, 2048);
  k_transpose<<<dim3(32, 16, 1), 256, 0, stream>>>(su, shUT, 1024, 2048);
  k_transpose<<<dim3(16, 32, 1), 256, 0, stream>>>(sd, shDT, 2048, 1024);
  k_router<<<2048, 256, 0, stream>>>(x, rw, bias, topk_idx, topk_w);
  k_route_post<<<1, 256, 0, stream>>>(topk_idx, offsets_, tile_expert, n_tiles,
                                      slot_token, tk_slot);
  // fused gate+up+silu for routed + shared "experts"
  k_gateup<<<dim3(8, GRID_Y), 256, 0, stream>>>(xb, gateT, upT, shGT, shUT, act,
                                                slot_token, tile_expert, n_tiles);
  // down for routed (-> yslot bf16) + shared (-> fp32 partial slabs)
  k_down<<<dim3(8, GRID_Y), 256, 0, stream>>>(act, downT, shDT, yslot, part,
                                              tile_expert, n_tiles);
  // out = p0+p1 + weighted routed
  k_gather<<<2048, 256, 0, stream>>>(out, part, yslot, tk_slot, topk_w);
}